// Round 1
// baseline (1925.654 us; speedup 1.0000x reference)
//
#include <hip/hip_runtime.h>
#include <math.h>

// ---------------------------------------------------------------------------
// xLSTM decoder block, MI355X gfx950.
// Pipeline (all flat (b*12+ch)*1024+l layout):
//  prep:  weights -> bf16 (Wg/upl/upr/down transposed to [n][k], Rg straight)
//  ln1:   x -> xn (fp32)                           [skip]
//  fc:    xn -> xc (fp32), x1 (fp32)               (conv12->12 k3 + 1x1)
//  ln2:   x1 -> xn2 (bf16)
//  gemm0: xn2 @ WgT + bg -> gx (bf16, 6144x4096)
//  rec:   block-diagonal sLSTM per (head, 8 batches), Rg in LDS, fused GroupNorm
//         -> hn (bf16, 6144x1024)
//  gemm0: hn @ WupT + [upl_b|upr_b] -> lr (bf16, 6144x2048)
//  gate:  glr = gelu(left)*right (bf16)
//  gemm2: glr @ WdT + down_b ; epilogue y = silu(xc)*(acc+down_b+x1) + xn
//  tail:  per-batch conv1+gelu+LN(len)+conv2+skip fully in LDS -> d_out
// ---------------------------------------------------------------------------

typedef short short8_t __attribute__((ext_vector_type(8)));
typedef unsigned uint4_t __attribute__((ext_vector_type(4)));
typedef float floatx4 __attribute__((ext_vector_type(4)));
typedef float float2_t __attribute__((ext_vector_type(2)));

static __device__ __forceinline__ float b2f(unsigned short u) {
    unsigned v = ((unsigned)u) << 16;
    return __builtin_bit_cast(float, v);
}
static __device__ __forceinline__ unsigned short f2b(float f) {
    unsigned u = __builtin_bit_cast(unsigned, f);
    u += 0x7FFFu + ((u >> 16) & 1u);   // RNE
    return (unsigned short)(u >> 16);
}
static __device__ __forceinline__ float2_t make2u(unsigned u) {
    float2_t r;
    r.x = __builtin_bit_cast(float, u << 16);
    r.y = __builtin_bit_cast(float, u & 0xFFFF0000u);
    return r;
}
static __device__ __forceinline__ float gelu_exact(float x) {
    return 0.5f * x * (1.f + erff(x * 0.70710678118654752f));
}

// --------------------------- weight prep ----------------------------------

__global__ __launch_bounds__(256) void transpose_bf16_k(
    const float* __restrict__ src, unsigned short* __restrict__ dst, int K, int N)
{   // dst[n*K+k] = bf16(src[k*N+n]); grid (N/32, K/32), block 256
    __shared__ unsigned short tl[32][33];
    const int n0 = blockIdx.x * 32, k0 = blockIdx.y * 32;
    const int tx = threadIdx.x & 31, ty = threadIdx.x >> 5; // ty 0..7
#pragma unroll
    for (int r = 0; r < 4; r++) {
        int k = ty + r * 8;
        tl[tx][k] = f2b(src[(size_t)(k0 + k) * N + n0 + tx]);
    }
    __syncthreads();
#pragma unroll
    for (int r = 0; r < 4; r++) {
        int n = ty * 4 + r;
        dst[(size_t)(n0 + n) * K + k0 + tx] = tl[n][tx];
    }
}

__global__ __launch_bounds__(256) void convert_bf16_k(
    const float* __restrict__ src, unsigned short* __restrict__ dst, int n)
{
    int gid = blockIdx.x * 256 + threadIdx.x;
    if (gid < n) dst[gid] = f2b(src[gid]);
}

__global__ __launch_bounds__(256) void cat_bias_k(
    const float* __restrict__ a, const float* __restrict__ b, float* __restrict__ o)
{
    int gid = blockIdx.x * 256 + threadIdx.x;   // 2048 total
    o[gid] = (gid < 1024) ? a[gid] : b[gid - 1024];
}

// ------------------------------ layernorm ----------------------------------

template <int BF16OUT>
__global__ __launch_bounds__(256) void ln_kernel(
    const float* __restrict__ in, const float* __restrict__ g,
    const float* __restrict__ be, void* __restrict__ outp)
{
    const int row = blockIdx.x;
    const float* xr = in + (size_t)row * 1024;
    const int t = threadIdx.x;
    float v[4];
    float s = 0.f, ss = 0.f;
#pragma unroll
    for (int u = 0; u < 4; u++) {
        float q = xr[t + u * 256];
        v[u] = q; s += q; ss += q * q;
    }
#pragma unroll
    for (int off = 32; off >= 1; off >>= 1) {
        s += __shfl_xor(s, off);
        ss += __shfl_xor(ss, off);
    }
    __shared__ float red[8];
    const int wv = t >> 6, la = t & 63;
    if (la == 0) { red[wv] = s; red[4 + wv] = ss; }
    __syncthreads();
    s = red[0] + red[1] + red[2] + red[3];
    ss = red[4] + red[5] + red[6] + red[7];
    float mu = s * (1.f / 1024.f);
    float var = ss * (1.f / 1024.f) - mu * mu;
    float rs = rsqrtf(var + 1e-5f);
#pragma unroll
    for (int u = 0; u < 4; u++) {
        int i = t + u * 256;
        float yv = (v[u] - mu) * rs * g[i] + be[i];
        if (BF16OUT)
            ((unsigned short*)outp)[(size_t)row * 1024 + i] = f2b(yv);
        else
            ((float*)outp)[(size_t)row * 1024 + i] = yv;
    }
}

// ---------------------- fc1 (conv k3) + fc2 (1x1) --------------------------

__global__ __launch_bounds__(256) void fc_kernel(
    const float* __restrict__ xn,
    const float* __restrict__ w1, const float* __restrict__ b1,
    const float* __restrict__ w2, const float* __restrict__ b2,
    float* __restrict__ xc, float* __restrict__ x1)
{
    __shared__ float sw1[432], sb1[12], sw2[144], sb2[12];
    const int t = threadIdx.x;
    for (int i = t; i < 432; i += 256) sw1[i] = w1[i];
    for (int i = t; i < 144; i += 256) sw2[i] = w2[i];
    if (t < 12) { sb1[t] = b1[t]; sb2[t] = b2[t]; }
    __syncthreads();
    const int gid = blockIdx.x * 256 + t;
    const int b = gid >> 10, l = gid & 1023;
    const float* xb = xn + (size_t)b * 12288;
    float inm[12], in0[12], inp[12];
#pragma unroll
    for (int ci = 0; ci < 12; ci++) {
        in0[ci] = xb[ci * 1024 + l];
        inm[ci] = (l > 0) ? xb[ci * 1024 + l - 1] : 0.f;
        inp[ci] = (l < 1023) ? xb[ci * 1024 + l + 1] : 0.f;
    }
    float xcv[12];
#pragma unroll
    for (int o = 0; o < 12; o++) {
        float a = sb1[o];
#pragma unroll
        for (int ci = 0; ci < 12; ci++) {
            const float* wp = &sw1[o * 36 + ci * 3];
            a += inm[ci] * wp[0] + in0[ci] * wp[1] + inp[ci] * wp[2];
        }
        xcv[o] = a;
        xc[(size_t)b * 12288 + o * 1024 + l] = a;
    }
#pragma unroll
    for (int o = 0; o < 12; o++) {
        float a = sb2[o];
#pragma unroll
        for (int ci = 0; ci < 12; ci++) a += xcv[ci] * sw2[o * 12 + ci];
        x1[(size_t)b * 12288 + o * 1024 + l] = a;
    }
}

// ------------------------------ bf16 GEMM ----------------------------------
// C[m][n] = sum_k A[m][k]*BT[n][k] + bias[n]; 128x128 tile, 4 waves 2x2,
// each wave 64x64 via 4x4 of mfma_f32_16x16x32_bf16.
// MODE 0: store bf16.  MODE 2: y = silu(xc)*(acc+bias+x1) + skip, store fp32.

template <int MODE>
__global__ __launch_bounds__(256) void gemm_kernel(
    const unsigned short* __restrict__ A, const unsigned short* __restrict__ BT,
    const float* __restrict__ bias, void* __restrict__ out,
    int M, int N, int K,
    const float* __restrict__ xc, const float* __restrict__ x1,
    const float* __restrict__ skip)
{
    __shared__ __align__(16) unsigned short sA[128 * 32];
    __shared__ __align__(16) unsigned short sB[128 * 32];
    const int t = threadIdx.x;
    const int m0 = blockIdx.y * 128;
    const int n0 = blockIdx.x * 128;
    const int w = t >> 6;
    const int lane = t & 63;
    const int wr = (w >> 1) * 64;
    const int wc = (w & 1) * 64;
    const int lrow = lane & 15;
    const int quad = lane >> 4;
    const int row_l = t >> 2;          // 0..63
    const int cs = (t & 3) * 8;        // 0,8,16,24

    floatx4 acc[4][4];
#pragma unroll
    for (int i = 0; i < 4; i++)
#pragma unroll
        for (int j = 0; j < 4; j++) acc[i][j] = (floatx4)0.f;

    for (int k0 = 0; k0 < K; k0 += 32) {
        __syncthreads();
        {
            short8_t va0 = *(const short8_t*)(A + (size_t)(m0 + row_l) * K + k0 + cs);
            short8_t va1 = *(const short8_t*)(A + (size_t)(m0 + row_l + 64) * K + k0 + cs);
            short8_t vb0 = *(const short8_t*)(BT + (size_t)(n0 + row_l) * K + k0 + cs);
            short8_t vb1 = *(const short8_t*)(BT + (size_t)(n0 + row_l + 64) * K + k0 + cs);
            *(short8_t*)(sA + row_l * 32 + cs) = va0;
            *(short8_t*)(sA + (row_l + 64) * 32 + cs) = va1;
            *(short8_t*)(sB + row_l * 32 + cs) = vb0;
            *(short8_t*)(sB + (row_l + 64) * 32 + cs) = vb1;
        }
        __syncthreads();
        short8_t af[4], bfr[4];
#pragma unroll
        for (int i = 0; i < 4; i++) {
            af[i] = *(const short8_t*)(sA + (wr + i * 16 + lrow) * 32 + quad * 8);
            bfr[i] = *(const short8_t*)(sB + (wc + i * 16 + lrow) * 32 + quad * 8);
        }
#pragma unroll
        for (int i = 0; i < 4; i++)
#pragma unroll
            for (int j = 0; j < 4; j++)
                acc[i][j] = __builtin_amdgcn_mfma_f32_16x16x32_bf16(
                    af[i], bfr[j], acc[i][j], 0, 0, 0);
    }

#pragma unroll
    for (int i = 0; i < 4; i++) {
#pragma unroll
        for (int j = 0; j < 4; j++) {
#pragma unroll
            for (int r = 0; r < 4; r++) {
                const int gm = m0 + wr + i * 16 + quad * 4 + r;
                const int gn = n0 + wc + j * 16 + lrow;
                const size_t idx = (size_t)gm * N + gn;
                float v = acc[i][j][r] + bias[gn];
                if (MODE == 0) {
                    ((unsigned short*)out)[idx] = f2b(v);
                } else {
                    float xcv = xc[idx];
                    float sig = xcv / (1.f + __expf(-xcv));
                    ((float*)out)[idx] = sig * (v + x1[idx]) + skip[idx];
                }
            }
        }
    }
}

// ------------------- sLSTM recurrence + GroupNorm (fused) ------------------
// grid (NH=8, B/8=64), block 256. Rg[head] bf16 in LDS (padded rows).
// thread t: hs = t&127, batches (t>>7)*4 .. +3; 12 steps sequential.

#define RSTRIDE 136

__global__ __launch_bounds__(256) void slstm_rec_kernel(
    const unsigned short* __restrict__ Rgb,   // [8][512][128] bf16
    const unsigned short* __restrict__ gxb,   // [B][12][4096] bf16
    const float* __restrict__ gn_g, const float* __restrict__ gn_b,
    unsigned short* __restrict__ hnb)         // [B][12][1024] bf16
{
    __shared__ __align__(16) unsigned short sR[512 * RSTRIDE];
    __shared__ __align__(16) float sH[8][128];
    const int head = blockIdx.x;
    const int b0 = blockIdx.y * 8;
    const int t = threadIdx.x;
    const unsigned short* Rh = Rgb + (size_t)head * 65536;
    for (int i = t; i < 512 * 16; i += 256) {
        int g = i >> 4, c = (i & 15) * 8;
        *(short8_t*)(sR + g * RSTRIDE + c) = *(const short8_t*)(Rh + g * 128 + c);
    }
    for (int i = t; i < 1024; i += 256) (&sH[0][0])[i] = 0.f;
    __syncthreads();

    const int hs = t & 127;
    const int hf = t >> 7;
    const int bb0 = hf * 4;
    float cst[4], nst[4], mst[4];
#pragma unroll
    for (int q = 0; q < 4; q++) { cst[q] = 0.f; nst[q] = 0.f; mst[q] = 0.f; }

    const unsigned short* rz = sR + (size_t)hs * RSTRIDE;
    const unsigned short* rri = sR + (size_t)(128 + hs) * RSTRIDE;
    const unsigned short* rrf = sR + (size_t)(256 + hs) * RSTRIDE;
    const unsigned short* rro = sR + (size_t)(384 + hs) * RSTRIDE;

    const int bb_g = t >> 5;   // GroupNorm phase: batch 0..7
    const int jg = t & 31;
    float gg[4], gb[4];
#pragma unroll
    for (int u = 0; u < 4; u++) {
        gg[u] = gn_g[head * 128 + jg + u * 32];
        gb[u] = gn_b[head * 128 + jg + u * 32];
    }

    for (int step = 0; step < 12; step++) {
        float2_t az[4], aiv[4], afv[4], aov[4];
#pragma unroll
        for (int q = 0; q < 4; q++) {
            az[q] = (float2_t)0.f; aiv[q] = (float2_t)0.f;
            afv[q] = (float2_t)0.f; aov[q] = (float2_t)0.f;
        }
#pragma unroll 4
        for (int k = 0; k < 128; k += 8) {
            uint4_t vz = *(const uint4_t*)(rz + k);
            uint4_t vi = *(const uint4_t*)(rri + k);
            uint4_t vf = *(const uint4_t*)(rrf + k);
            uint4_t vo = *(const uint4_t*)(rro + k);
            float2_t fz[4], fi[4], ff[4], fo[4];
#pragma unroll
            for (int p = 0; p < 4; p++) {
                fz[p] = make2u(vz[p]); fi[p] = make2u(vi[p]);
                ff[p] = make2u(vf[p]); fo[p] = make2u(vo[p]);
            }
#pragma unroll
            for (int q = 0; q < 4; q++) {
                const float* hb = &sH[bb0 + q][k];
                float2_t h0 = *(const float2_t*)(hb);
                float2_t h1 = *(const float2_t*)(hb + 2);
                float2_t h2 = *(const float2_t*)(hb + 4);
                float2_t h3 = *(const float2_t*)(hb + 6);
                az[q] += fz[0] * h0 + fz[1] * h1 + fz[2] * h2 + fz[3] * h3;
                aiv[q] += fi[0] * h0 + fi[1] * h1 + fi[2] * h2 + fi[3] * h3;
                afv[q] += ff[0] * h0 + ff[1] * h1 + ff[2] * h2 + ff[3] * h3;
                aov[q] += fo[0] * h0 + fo[1] * h1 + fo[2] * h2 + fo[3] * h3;
            }
        }
        float hv[4];
#pragma unroll
        for (int q = 0; q < 4; q++) {
            const unsigned short* gp =
                gxb + ((size_t)(b0 + bb0 + q) * 12 + step) * 4096 + head * 512;
            float zp = b2f(gp[hs]) + az[q].x + az[q].y;
            float ip = b2f(gp[128 + hs]) + aiv[q].x + aiv[q].y;
            float fp = b2f(gp[256 + hs]) + afv[q].x + afv[q].y;
            float op = b2f(gp[384 + hs]) + aov[q].x + aov[q].y;
            float e2 = __expf(2.f * zp);
            float z = (e2 - 1.f) / (e2 + 1.f);
            float o = 1.f / (1.f + __expf(-op));
            float mn = fmaxf(fp + mst[q], ip);
            float ie = __expf(ip - mn);
            float fe = __expf(fp + mst[q] - mn);
            cst[q] = fe * cst[q] + ie * z;
            nst[q] = fe * nst[q] + ie;
            mst[q] = mn;
            hv[q] = o * (cst[q] / nst[q]);
        }
        __syncthreads();   // prior-step sH fully consumed
#pragma unroll
        for (int q = 0; q < 4; q++) sH[bb0 + q][hs] = hv[q];
        __syncthreads();   // sH complete for GN + next step
        {
            float vv[4];
#pragma unroll
            for (int u = 0; u < 4; u++) vv[u] = sH[bb_g][jg + u * 32];
            float s = vv[0] + vv[1] + vv[2] + vv[3];
            float ss = vv[0] * vv[0] + vv[1] * vv[1] + vv[2] * vv[2] + vv[3] * vv[3];
#pragma unroll
            for (int off = 16; off >= 1; off >>= 1) {
                s += __shfl_xor(s, off);
                ss += __shfl_xor(ss, off);
            }
            float mu = s * (1.f / 128.f);
            float var = ss * (1.f / 128.f) - mu * mu;
            float rs = rsqrtf(var + 1e-5f);
            size_t base = ((size_t)(b0 + bb_g) * 12 + step) * 1024 + head * 128;
#pragma unroll
            for (int u = 0; u < 4; u++) {
                float hn = (vv[u] - mu) * rs * gg[u] + gb[u];
                hnb[base + jg + u * 32] = f2b(hn);
            }
        }
    }
}

// ------------------------------ gate kernel --------------------------------

__global__ __launch_bounds__(256) void gate_kernel(
    const unsigned short* __restrict__ lr, unsigned short* __restrict__ glr)
{
    size_t gid = (size_t)blockIdx.x * 256 + threadIdx.x;  // 6144*1024
    size_t m = gid >> 10;
    int j = (int)(gid & 1023);
    float lf = b2f(lr[m * 2048 + j]);
    float rt = b2f(lr[m * 2048 + 1024 + j]);
    glr[gid] = f2b(gelu_exact(lf) * rt);
}

// ----------------------- tail: conv1+gelu+LN+conv2+skip --------------------
// one block per batch, 512 threads; thread covers l = 2t, 2t+1.

__global__ __launch_bounds__(512) void tail_kernel(
    const float* __restrict__ y, const float* __restrict__ skip,
    const float* __restrict__ w1, const float* __restrict__ b1,
    const float* __restrict__ w2, const float* __restrict__ b2,
    const float* __restrict__ lng, const float* __restrict__ lnb,
    float* __restrict__ out)
{
    __shared__ unsigned short sY[12][1024];   // 24 KB
    __shared__ unsigned short sG[48][1024];   // 96 KB
    __shared__ float sW1[1728], sB1[48], sW2[1728], sB2[12];
    const int b = blockIdx.x;
    const int t = threadIdx.x;
    for (int i = t; i < 12 * 1024; i += 512) sY[0][i] = f2b(y[(size_t)b * 12288 + i]);
    for (int i = t; i < 1728; i += 512) { sW1[i] = w1[i]; sW2[i] = w2[i]; }
    if (t < 48) sB1[t] = b1[t];
    if (t < 12) sB2[t] = b2[t];
    __syncthreads();

    const int l0 = t * 2;
    // conv1 (12->48, k3) + gelu
    for (int o = 0; o < 48; o++) {
        float a0 = sB1[o], a1 = sB1[o];
#pragma unroll
        for (int ci = 0; ci < 12; ci++) {
            const float* wp = &sW1[o * 36 + ci * 3];
            float xm = (l0 > 0) ? b2f(sY[ci][l0 - 1]) : 0.f;
            float x0 = b2f(sY[ci][l0]);
            float xp = b2f(sY[ci][l0 + 1]);
            float x2 = (l0 + 2 < 1024) ? b2f(sY[ci][l0 + 2]) : 0.f;
            a0 += xm * wp[0] + x0 * wp[1] + xp * wp[2];
            a1 += x0 * wp[0] + xp * wp[1] + x2 * wp[2];
        }
        sG[o][l0] = f2b(gelu_exact(a0));
        sG[o][l0 + 1] = f2b(gelu_exact(a1));
    }
    __syncthreads();
    // LayerNorm over length per row (ln_g/ln_b indexed by position l)
    {
        const int wv = t >> 6, la = t & 63;
        for (int o = wv; o < 48; o += 8) {
            float vb[16];
            float s = 0.f, ss = 0.f;
#pragma unroll
            for (int u = 0; u < 16; u++) {
                float v = b2f(sG[o][la + u * 64]);
                vb[u] = v; s += v; ss += v * v;
            }
#pragma unroll
            for (int off = 32; off >= 1; off >>= 1) {
                s += __shfl_xor(s, off);
                ss += __shfl_xor(ss, off);
            }
            float mu = s * (1.f / 1024.f);
            float var = ss * (1.f / 1024.f) - mu * mu;
            float rs = rsqrtf(var + 1e-5f);
#pragma unroll
            for (int u = 0; u < 16; u++) {
                int l = la + u * 64;
                sG[o][l] = f2b((vb[u] - mu) * rs * lng[l] + lnb[l]);
            }
        }
    }
    __syncthreads();
    // conv2 (48->12, k3) + skip
    for (int o = 0; o < 12; o++) {
        float a0 = sB2[o], a1 = sB2[o];
#pragma unroll
        for (int ci = 0; ci < 48; ci++) {
            const float* wp = &sW2[o * 144 + ci * 3];
            float xm = (l0 > 0) ? b2f(sG[ci][l0 - 1]) : 0.f;
            float x0 = b2f(sG[ci][l0]);
            float xp = b2f(sG[ci][l0 + 1]);
            float x2 = (l0 + 2 < 1024) ? b2f(sG[ci][l0 + 2]) : 0.f;
            a0 += xm * wp[0] + x0 * wp[1] + xp * wp[2];
            a1 += x0 * wp[0] + xp * wp[1] + x2 * wp[2];
        }
        size_t idx = (size_t)b * 12288 + o * 1024 + l0;
        out[idx] = a0 + skip[idx];
        out[idx + 1] = a1 + skip[idx + 1];
    }
}

// ------------------------------ launcher -----------------------------------

extern "C" void kernel_launch(void* const* d_in, const int* in_sizes, int n_in,
                              void* d_out, int out_size, void* d_ws, size_t ws_size,
                              hipStream_t stream)
{
    (void)in_sizes; (void)n_in; (void)out_size; (void)ws_size;
    const float* x      = (const float*)d_in[0];
    const float* ln_g   = (const float*)d_in[1];
    const float* ln_b   = (const float*)d_in[2];
    const float* fc1_w  = (const float*)d_in[3];
    const float* fc1_b  = (const float*)d_in[4];
    const float* fc2_w  = (const float*)d_in[5];
    const float* fc2_b  = (const float*)d_in[6];
    const float* conv1_w= (const float*)d_in[7];
    const float* conv1_b= (const float*)d_in[8];
    const float* conv2_w= (const float*)d_in[9];
    const float* conv2_b= (const float*)d_in[10];
    const float* xl_g   = (const float*)d_in[11];
    const float* xl_b   = (const float*)d_in[12];
    const float* Wg     = (const float*)d_in[13];
    const float* bg     = (const float*)d_in[14];
    const float* Rg     = (const float*)d_in[15];
    const float* gn_g   = (const float*)d_in[16];
    const float* gn_b   = (const float*)d_in[17];
    const float* upl_w  = (const float*)d_in[18];
    const float* upl_b  = (const float*)d_in[19];
    const float* upr_w  = (const float*)d_in[20];
    const float* upr_b  = (const float*)d_in[21];
    const float* down_w = (const float*)d_in[22];
    const float* down_b = (const float*)d_in[23];

    char* ws = (char*)d_ws;
    size_t off = 0;
    auto alloc = [&](size_t bytes) -> char* {
        char* p = ws + off;
        off = (off + bytes + 255) & ~(size_t)255;
        return p;
    };
    float* xn            = (float*)alloc(25165824);          // 6144x1024 f32
    float* xc            = (float*)alloc(25165824);
    float* x1            = (float*)alloc(25165824);
    unsigned short* xn2b = (unsigned short*)alloc(12582912); // 6144x1024 bf16
    unsigned short* gxb  = (unsigned short*)alloc(50331648); // 6144x4096 bf16
    unsigned short* hnb  = (unsigned short*)alloc(12582912);
    unsigned short* lrb  = (unsigned short*)alloc(25165824); // 6144x2048 bf16
    unsigned short* glrb = (unsigned short*)alloc(12582912);
    float* yb            = (float*)alloc(25165824);
    unsigned short* WgT  = (unsigned short*)alloc(8388608);  // 4096x1024 bf16
    unsigned short* WupT = (unsigned short*)alloc(4194304);  // 2048x1024 bf16
    unsigned short* WdT  = (unsigned short*)alloc(2097152);  // 1024x1024 bf16
    unsigned short* Rgb  = (unsigned short*)alloc(1048576);  // 8x512x128 bf16
    float* bup           = (float*)alloc(8192);              // 2048 f32

    // weight prep
    transpose_bf16_k<<<dim3(128, 32), 256, 0, stream>>>(Wg, WgT, 1024, 4096);
    transpose_bf16_k<<<dim3(32, 32), 256, 0, stream>>>(upl_w, WupT, 1024, 1024);
    transpose_bf16_k<<<dim3(32, 32), 256, 0, stream>>>(upr_w, WupT + 1024 * 1024, 1024, 1024);
    transpose_bf16_k<<<dim3(32, 32), 256, 0, stream>>>(down_w, WdT, 1024, 1024);
    convert_bf16_k<<<2048, 256, 0, stream>>>(Rg, Rgb, 524288);
    cat_bias_k<<<8, 256, 0, stream>>>(upl_b, upr_b, bup);

    // main pipeline
    ln_kernel<0><<<6144, 256, 0, stream>>>(x, ln_g, ln_b, xn);
    fc_kernel<<<2048, 256, 0, stream>>>(xn, fc1_w, fc1_b, fc2_w, fc2_b, xc, x1);
    ln_kernel<1><<<6144, 256, 0, stream>>>(x1, xl_g, xl_b, xn2b);
    gemm_kernel<0><<<dim3(32, 48), 256, 0, stream>>>(
        xn2b, WgT, bg, gxb, 6144, 4096, 1024, nullptr, nullptr, nullptr);
    slstm_rec_kernel<<<dim3(8, 64), 256, 0, stream>>>(Rgb, gxb, gn_g, gn_b, hnb);
    gemm_kernel<0><<<dim3(16, 48), 256, 0, stream>>>(
        hnb, WupT, bup, lrb, 6144, 2048, 1024, nullptr, nullptr, nullptr);
    gate_kernel<<<24576, 256, 0, stream>>>(lrb, glrb);
    gemm_kernel<2><<<dim3(8, 48), 256, 0, stream>>>(
        glrb, WdT, down_b, yb, 6144, 1024, 1024, xc, x1, xn);
    tail_kernel<<<512, 512, 0, stream>>>(
        yb, xn, conv1_w, conv1_b, conv2_w, conv2_b, ln_g, ln_b, (float*)d_out);
}

// Round 2
// 740.916 us; speedup vs baseline: 2.5990x; 2.5990x over previous
//
#include <hip/hip_runtime.h>
#include <math.h>

// ---------------------------------------------------------------------------
// xLSTM decoder block, MI355X gfx950.
// Pipeline (all flat (b*12+ch)*1024+l layout):
//  prep:  weights -> bf16 (Wg/upl/upr/down transposed to [n][k], Rg straight)
//  ln1:   x -> xn (fp32)                           [skip]
//  fc:    xn -> xc (fp32), x1 (fp32)               (conv12->12 k3 + 1x1)
//  ln2:   x1 -> xn2 (bf16)
//  gemm0: xn2 @ WgT + bg -> gx (bf16, 6144x4096)
//  rec:   block-diagonal sLSTM per (head, 8 batches), Rg in LDS, fused GroupNorm
//         -> hn (bf16, 6144x1024)
//  gemm0: hn @ WupT + [upl_b|upr_b] -> lr (bf16, 6144x2048)
//  gate:  glr = gelu(left)*right (bf16)
//  gemm2: glr @ WdT + down_b ; epilogue y = silu(xc)*(acc+down_b+x1) + xn
//  tailA: conv1+gelu+LN(len) per (batch, 8-channel chunk) -> z bf16 (reuses gxb)
//  tailB: conv2(48->12)+skip per (batch, 256-pos tile)    -> d_out
// Round-2 change: old monolithic tail_kernel spilled ~1.7GB/launch of scratch
// (FETCH~=WRITE~=1.76GB vs 75MB intended). Split into two spill-free kernels:
// values in registers, conv weights via wave-uniform s_load (SGPR operands).
// ---------------------------------------------------------------------------

typedef short short8_t __attribute__((ext_vector_type(8)));
typedef unsigned uint4_t __attribute__((ext_vector_type(4)));
typedef float floatx4 __attribute__((ext_vector_type(4)));
typedef float float2_t __attribute__((ext_vector_type(2)));
typedef float float4_t __attribute__((ext_vector_type(4)));

static __device__ __forceinline__ float b2f(unsigned short u) {
    unsigned v = ((unsigned)u) << 16;
    return __builtin_bit_cast(float, v);
}
static __device__ __forceinline__ unsigned short f2b(float f) {
    unsigned u = __builtin_bit_cast(unsigned, f);
    u += 0x7FFFu + ((u >> 16) & 1u);   // RNE
    return (unsigned short)(u >> 16);
}
static __device__ __forceinline__ float2_t make2u(unsigned u) {
    float2_t r;
    r.x = __builtin_bit_cast(float, u << 16);
    r.y = __builtin_bit_cast(float, u & 0xFFFF0000u);
    return r;
}
static __device__ __forceinline__ float gelu_exact(float x) {
    return 0.5f * x * (1.f + erff(x * 0.70710678118654752f));
}

// --------------------------- weight prep ----------------------------------

__global__ __launch_bounds__(256) void transpose_bf16_k(
    const float* __restrict__ src, unsigned short* __restrict__ dst, int K, int N)
{   // dst[n*K+k] = bf16(src[k*N+n]); grid (N/32, K/32), block 256
    __shared__ unsigned short tl[32][33];
    const int n0 = blockIdx.x * 32, k0 = blockIdx.y * 32;
    const int tx = threadIdx.x & 31, ty = threadIdx.x >> 5; // ty 0..7
#pragma unroll
    for (int r = 0; r < 4; r++) {
        int k = ty + r * 8;
        tl[tx][k] = f2b(src[(size_t)(k0 + k) * N + n0 + tx]);
    }
    __syncthreads();
#pragma unroll
    for (int r = 0; r < 4; r++) {
        int n = ty * 4 + r;
        dst[(size_t)(n0 + n) * K + k0 + tx] = tl[n][tx];
    }
}

__global__ __launch_bounds__(256) void convert_bf16_k(
    const float* __restrict__ src, unsigned short* __restrict__ dst, int n)
{
    int gid = blockIdx.x * 256 + threadIdx.x;
    if (gid < n) dst[gid] = f2b(src[gid]);
}

__global__ __launch_bounds__(256) void cat_bias_k(
    const float* __restrict__ a, const float* __restrict__ b, float* __restrict__ o)
{
    int gid = blockIdx.x * 256 + threadIdx.x;   // 2048 total
    o[gid] = (gid < 1024) ? a[gid] : b[gid - 1024];
}

// ------------------------------ layernorm ----------------------------------

template <int BF16OUT>
__global__ __launch_bounds__(256) void ln_kernel(
    const float* __restrict__ in, const float* __restrict__ g,
    const float* __restrict__ be, void* __restrict__ outp)
{
    const int row = blockIdx.x;
    const float* xr = in + (size_t)row * 1024;
    const int t = threadIdx.x;
    float v[4];
    float s = 0.f, ss = 0.f;
#pragma unroll
    for (int u = 0; u < 4; u++) {
        float q = xr[t + u * 256];
        v[u] = q; s += q; ss += q * q;
    }
#pragma unroll
    for (int off = 32; off >= 1; off >>= 1) {
        s += __shfl_xor(s, off);
        ss += __shfl_xor(ss, off);
    }
    __shared__ float red[8];
    const int wv = t >> 6, la = t & 63;
    if (la == 0) { red[wv] = s; red[4 + wv] = ss; }
    __syncthreads();
    s = red[0] + red[1] + red[2] + red[3];
    ss = red[4] + red[5] + red[6] + red[7];
    float mu = s * (1.f / 1024.f);
    float var = ss * (1.f / 1024.f) - mu * mu;
    float rs = rsqrtf(var + 1e-5f);
#pragma unroll
    for (int u = 0; u < 4; u++) {
        int i = t + u * 256;
        float yv = (v[u] - mu) * rs * g[i] + be[i];
        if (BF16OUT)
            ((unsigned short*)outp)[(size_t)row * 1024 + i] = f2b(yv);
        else
            ((float*)outp)[(size_t)row * 1024 + i] = yv;
    }
}

// ---------------------- fc1 (conv k3) + fc2 (1x1) --------------------------

__global__ __launch_bounds__(256) void fc_kernel(
    const float* __restrict__ xn,
    const float* __restrict__ w1, const float* __restrict__ b1,
    const float* __restrict__ w2, const float* __restrict__ b2,
    float* __restrict__ xc, float* __restrict__ x1)
{
    const int t = threadIdx.x;
    const int gid = blockIdx.x * 256 + t;
    const int b = gid >> 10, l = gid & 1023;
    const float* xb = xn + (size_t)b * 12288;
    float inm[12], in0[12], inp[12];
#pragma unroll
    for (int ci = 0; ci < 12; ci++) {
        in0[ci] = xb[ci * 1024 + l];
        inm[ci] = (l > 0) ? xb[ci * 1024 + l - 1] : 0.f;
        inp[ci] = (l < 1023) ? xb[ci * 1024 + l + 1] : 0.f;
    }
    float xcv[12];
#pragma unroll
    for (int o = 0; o < 12; o++) {
        float a = b1[o];
#pragma unroll
        for (int ci = 0; ci < 12; ci++) {
            const float* wp = w1 + o * 36 + ci * 3;  // uniform -> s_load
            a += inm[ci] * wp[0] + in0[ci] * wp[1] + inp[ci] * wp[2];
        }
        xcv[o] = a;
        xc[(size_t)b * 12288 + o * 1024 + l] = a;
    }
#pragma unroll
    for (int o = 0; o < 12; o++) {
        float a = b2[o];
#pragma unroll
        for (int ci = 0; ci < 12; ci++) a += xcv[ci] * w2[o * 12 + ci];
        x1[(size_t)b * 12288 + o * 1024 + l] = a;
    }
}

// ------------------------------ bf16 GEMM ----------------------------------
// C[m][n] = sum_k A[m][k]*BT[n][k] + bias[n]; 128x128 tile, 4 waves 2x2,
// each wave 64x64 via 4x4 of mfma_f32_16x16x32_bf16.
// MODE 0: store bf16.  MODE 2: y = silu(xc)*(acc+bias+x1) + skip, store fp32.

template <int MODE>
__global__ __launch_bounds__(256) void gemm_kernel(
    const unsigned short* __restrict__ A, const unsigned short* __restrict__ BT,
    const float* __restrict__ bias, void* __restrict__ out,
    int M, int N, int K,
    const float* __restrict__ xc, const float* __restrict__ x1,
    const float* __restrict__ skip)
{
    __shared__ __align__(16) unsigned short sA[128 * 32];
    __shared__ __align__(16) unsigned short sB[128 * 32];
    const int t = threadIdx.x;
    const int m0 = blockIdx.y * 128;
    const int n0 = blockIdx.x * 128;
    const int w = t >> 6;
    const int lane = t & 63;
    const int wr = (w >> 1) * 64;
    const int wc = (w & 1) * 64;
    const int lrow = lane & 15;
    const int quad = lane >> 4;
    const int row_l = t >> 2;          // 0..63
    const int cs = (t & 3) * 8;        // 0,8,16,24

    floatx4 acc[4][4];
#pragma unroll
    for (int i = 0; i < 4; i++)
#pragma unroll
        for (int j = 0; j < 4; j++) acc[i][j] = (floatx4)0.f;

    for (int k0 = 0; k0 < K; k0 += 32) {
        __syncthreads();
        {
            short8_t va0 = *(const short8_t*)(A + (size_t)(m0 + row_l) * K + k0 + cs);
            short8_t va1 = *(const short8_t*)(A + (size_t)(m0 + row_l + 64) * K + k0 + cs);
            short8_t vb0 = *(const short8_t*)(BT + (size_t)(n0 + row_l) * K + k0 + cs);
            short8_t vb1 = *(const short8_t*)(BT + (size_t)(n0 + row_l + 64) * K + k0 + cs);
            *(short8_t*)(sA + row_l * 32 + cs) = va0;
            *(short8_t*)(sA + (row_l + 64) * 32 + cs) = va1;
            *(short8_t*)(sB + row_l * 32 + cs) = vb0;
            *(short8_t*)(sB + (row_l + 64) * 32 + cs) = vb1;
        }
        __syncthreads();
        short8_t af[4], bfr[4];
#pragma unroll
        for (int i = 0; i < 4; i++) {
            af[i] = *(const short8_t*)(sA + (wr + i * 16 + lrow) * 32 + quad * 8);
            bfr[i] = *(const short8_t*)(sB + (wc + i * 16 + lrow) * 32 + quad * 8);
        }
#pragma unroll
        for (int i = 0; i < 4; i++)
#pragma unroll
            for (int j = 0; j < 4; j++)
                acc[i][j] = __builtin_amdgcn_mfma_f32_16x16x32_bf16(
                    af[i], bfr[j], acc[i][j], 0, 0, 0);
    }

#pragma unroll
    for (int i = 0; i < 4; i++) {
#pragma unroll
        for (int j = 0; j < 4; j++) {
#pragma unroll
            for (int r = 0; r < 4; r++) {
                const int gm = m0 + wr + i * 16 + quad * 4 + r;
                const int gn = n0 + wc + j * 16 + lrow;
                const size_t idx = (size_t)gm * N + gn;
                float v = acc[i][j][r] + bias[gn];
                if (MODE == 0) {
                    ((unsigned short*)out)[idx] = f2b(v);
                } else {
                    float xcv = xc[idx];
                    float sig = xcv / (1.f + __expf(-xcv));
                    ((float*)out)[idx] = sig * (v + x1[idx]) + skip[idx];
                }
            }
        }
    }
}

// ------------------- sLSTM recurrence + GroupNorm (fused) ------------------
// grid (NH=8, B/8=64), block 256. Rg[head] bf16 in LDS (padded rows).
// thread t: hs = t&127, batches (t>>7)*4 .. +3; 12 steps sequential.

#define RSTRIDE 136

__global__ __launch_bounds__(256) void slstm_rec_kernel(
    const unsigned short* __restrict__ Rgb,   // [8][512][128] bf16
    const unsigned short* __restrict__ gxb,   // [B][12][4096] bf16
    const float* __restrict__ gn_g, const float* __restrict__ gn_b,
    unsigned short* __restrict__ hnb)         // [B][12][1024] bf16
{
    __shared__ __align__(16) unsigned short sR[512 * RSTRIDE];
    __shared__ __align__(16) float sH[8][128];
    const int head = blockIdx.x;
    const int b0 = blockIdx.y * 8;
    const int t = threadIdx.x;
    const unsigned short* Rh = Rgb + (size_t)head * 65536;
    for (int i = t; i < 512 * 16; i += 256) {
        int g = i >> 4, c = (i & 15) * 8;
        *(short8_t*)(sR + g * RSTRIDE + c) = *(const short8_t*)(Rh + g * 128 + c);
    }
    for (int i = t; i < 1024; i += 256) (&sH[0][0])[i] = 0.f;
    __syncthreads();

    const int hs = t & 127;
    const int hf = t >> 7;
    const int bb0 = hf * 4;
    float cst[4], nst[4], mst[4];
#pragma unroll
    for (int q = 0; q < 4; q++) { cst[q] = 0.f; nst[q] = 0.f; mst[q] = 0.f; }

    const unsigned short* rz = sR + (size_t)hs * RSTRIDE;
    const unsigned short* rri = sR + (size_t)(128 + hs) * RSTRIDE;
    const unsigned short* rrf = sR + (size_t)(256 + hs) * RSTRIDE;
    const unsigned short* rro = sR + (size_t)(384 + hs) * RSTRIDE;

    const int bb_g = t >> 5;   // GroupNorm phase: batch 0..7
    const int jg = t & 31;
    float gg[4], gb[4];
#pragma unroll
    for (int u = 0; u < 4; u++) {
        gg[u] = gn_g[head * 128 + jg + u * 32];
        gb[u] = gn_b[head * 128 + jg + u * 32];
    }

    for (int step = 0; step < 12; step++) {
        float2_t az[4], aiv[4], afv[4], aov[4];
#pragma unroll
        for (int q = 0; q < 4; q++) {
            az[q] = (float2_t)0.f; aiv[q] = (float2_t)0.f;
            afv[q] = (float2_t)0.f; aov[q] = (float2_t)0.f;
        }
#pragma unroll 4
        for (int k = 0; k < 128; k += 8) {
            uint4_t vz = *(const uint4_t*)(rz + k);
            uint4_t vi = *(const uint4_t*)(rri + k);
            uint4_t vf = *(const uint4_t*)(rrf + k);
            uint4_t vo = *(const uint4_t*)(rro + k);
            float2_t fz[4], fi[4], ff[4], fo[4];
#pragma unroll
            for (int p = 0; p < 4; p++) {
                fz[p] = make2u(vz[p]); fi[p] = make2u(vi[p]);
                ff[p] = make2u(vf[p]); fo[p] = make2u(vo[p]);
            }
#pragma unroll
            for (int q = 0; q < 4; q++) {
                const float* hb = &sH[bb0 + q][k];
                float2_t h0 = *(const float2_t*)(hb);
                float2_t h1 = *(const float2_t*)(hb + 2);
                float2_t h2 = *(const float2_t*)(hb + 4);
                float2_t h3 = *(const float2_t*)(hb + 6);
                az[q] += fz[0] * h0 + fz[1] * h1 + fz[2] * h2 + fz[3] * h3;
                aiv[q] += fi[0] * h0 + fi[1] * h1 + fi[2] * h2 + fi[3] * h3;
                afv[q] += ff[0] * h0 + ff[1] * h1 + ff[2] * h2 + ff[3] * h3;
                aov[q] += fo[0] * h0 + fo[1] * h1 + fo[2] * h2 + fo[3] * h3;
            }
        }
        float hv[4];
#pragma unroll
        for (int q = 0; q < 4; q++) {
            const unsigned short* gp =
                gxb + ((size_t)(b0 + bb0 + q) * 12 + step) * 4096 + head * 512;
            float zp = b2f(gp[hs]) + az[q].x + az[q].y;
            float ip = b2f(gp[128 + hs]) + aiv[q].x + aiv[q].y;
            float fp = b2f(gp[256 + hs]) + afv[q].x + afv[q].y;
            float op = b2f(gp[384 + hs]) + aov[q].x + aov[q].y;
            float e2 = __expf(2.f * zp);
            float z = (e2 - 1.f) / (e2 + 1.f);
            float o = 1.f / (1.f + __expf(-op));
            float mn = fmaxf(fp + mst[q], ip);
            float ie = __expf(ip - mn);
            float fe = __expf(fp + mst[q] - mn);
            cst[q] = fe * cst[q] + ie * z;
            nst[q] = fe * nst[q] + ie;
            mst[q] = mn;
            hv[q] = o * (cst[q] / nst[q]);
        }
        __syncthreads();   // prior-step sH fully consumed
#pragma unroll
        for (int q = 0; q < 4; q++) sH[bb0 + q][hs] = hv[q];
        __syncthreads();   // sH complete for GN + next step
        {
            float vv[4];
#pragma unroll
            for (int u = 0; u < 4; u++) vv[u] = sH[bb_g][jg + u * 32];
            float s = vv[0] + vv[1] + vv[2] + vv[3];
            float ss = vv[0] * vv[0] + vv[1] * vv[1] + vv[2] * vv[2] + vv[3] * vv[3];
#pragma unroll
            for (int off = 16; off >= 1; off >>= 1) {
                s += __shfl_xor(s, off);
                ss += __shfl_xor(ss, off);
            }
            float mu = s * (1.f / 128.f);
            float var = ss * (1.f / 128.f) - mu * mu;
            float rs = rsqrtf(var + 1e-5f);
            size_t base = ((size_t)(b0 + bb_g) * 12 + step) * 1024 + head * 128;
#pragma unroll
            for (int u = 0; u < 4; u++) {
                float hn = (vv[u] - mu) * rs * gg[u] + gb[u];
                hnb[base + jg + u * 32] = f2b(hn);
            }
        }
    }
}

// ------------------------------ gate kernel --------------------------------

__global__ __launch_bounds__(256) void gate_kernel(
    const unsigned short* __restrict__ lr, unsigned short* __restrict__ glr)
{
    size_t gid = (size_t)blockIdx.x * 256 + threadIdx.x;  // 6144*1024
    size_t m = gid >> 10;
    int j = (int)(gid & 1023);
    float lf = b2f(lr[m * 2048 + j]);
    float rt = b2f(lr[m * 2048 + 1024 + j]);
    glr[gid] = f2b(gelu_exact(lf) * rt);
}

// ------------------ tail A: conv1(12->48)+gelu+LN(length) ------------------
// grid (512 batches, 6 chunks of 8 out-channels), block 256.
// Values in registers, weights via wave-uniform s_load. Spill-free by design.

__global__ __launch_bounds__(256) void tail_conv1_ln_kernel(
    const float* __restrict__ y, const float* __restrict__ w1,
    const float* __restrict__ b1, const float* __restrict__ lng,
    const float* __restrict__ lnb, unsigned short* __restrict__ z)
{
    __shared__ float sX[12 * 1024];          // 48 KB
    __shared__ unsigned short sZ[8][1024];   // 16 KB
    __shared__ float sred[2][8][4];
    const int b = blockIdx.x;
    const int o0 = blockIdx.y * 8;
    const int t = threadIdx.x;

    const float4_t* srcv = (const float4_t*)(y + (size_t)b * 12288);
    float4_t* dstv = (float4_t*)sX;
    for (int i = t; i < 3072; i += 256) dstv[i] = srcv[i];
    __syncthreads();

    float s[8], ss[8];
#pragma unroll
    for (int o = 0; o < 8; o++) { s[o] = 0.f; ss[o] = 0.f; }

    for (int p = 0; p < 4; p++) {
        const int l = t + p * 256;
        float vm[12], v0[12], vp[12];
#pragma unroll
        for (int ci = 0; ci < 12; ci++) {
            v0[ci] = sX[ci * 1024 + l];
            vm[ci] = (l > 0) ? sX[ci * 1024 + l - 1] : 0.f;
            vp[ci] = (l < 1023) ? sX[ci * 1024 + l + 1] : 0.f;
        }
#pragma unroll
        for (int o = 0; o < 8; o++) {
            const float* wp = w1 + (o0 + o) * 36;   // uniform -> SGPR
            float a = b1[o0 + o];
#pragma unroll
            for (int ci = 0; ci < 12; ci++)
                a += vm[ci] * wp[ci * 3] + v0[ci] * wp[ci * 3 + 1] + vp[ci] * wp[ci * 3 + 2];
            float g = gelu_exact(a);
            s[o] += g; ss[o] += g * g;
            sZ[o][l] = f2b(g);
        }
    }
    // block reduction of per-row stats
    const int wv = t >> 6, la = t & 63;
#pragma unroll
    for (int o = 0; o < 8; o++) {
        float a = s[o], q = ss[o];
#pragma unroll
        for (int off = 32; off >= 1; off >>= 1) {
            a += __shfl_xor(a, off);
            q += __shfl_xor(q, off);
        }
        if (la == 0) { sred[0][o][wv] = a; sred[1][o][wv] = q; }
    }
    __syncthreads();
    float mu[8], rs[8];
#pragma unroll
    for (int o = 0; o < 8; o++) {
        float S = sred[0][o][0] + sred[0][o][1] + sred[0][o][2] + sred[0][o][3];
        float Q = sred[1][o][0] + sred[1][o][1] + sred[1][o][2] + sred[1][o][3];
        float m = S * (1.f / 1024.f);
        float var = Q * (1.f / 1024.f) - m * m;
        mu[o] = m;
        rs[o] = rsqrtf(var + 1e-5f);
    }
    for (int p = 0; p < 4; p++) {
        const int l = t + p * 256;
        const float lg = lng[l], lb = lnb[l];
#pragma unroll
        for (int o = 0; o < 8; o++) {
            float v = b2f(sZ[o][l]);
            z[((size_t)b * 48 + o0 + o) * 1024 + l] = f2b((v - mu[o]) * rs[o] * lg + lb);
        }
    }
}

// -------------------- tail B: conv2(48->12) + skip -------------------------
// grid (512 batches, 4 tiles of 256 positions), block 256.

__global__ __launch_bounds__(256) void tail_conv2_kernel(
    const unsigned short* __restrict__ z, const float* __restrict__ skip,
    const float* __restrict__ w2, const float* __restrict__ b2,
    float* __restrict__ out)
{
    __shared__ unsigned short sZt[48][258];
    const int b = blockIdx.x;
    const int l0 = blockIdx.y * 256;
    const int t = threadIdx.x;
    const unsigned short* zb = z + (size_t)b * 49152;
    for (int ci = 0; ci < 48; ci++) {
        int l = l0 - 1 + t;
        sZt[ci][t] = (l >= 0 && l < 1024) ? zb[ci * 1024 + l] : (unsigned short)0;
        if (t < 2) {
            int l2 = l0 - 1 + 256 + t;
            sZt[ci][256 + t] = (l2 >= 0 && l2 < 1024) ? zb[ci * 1024 + l2] : (unsigned short)0;
        }
    }
    __syncthreads();
    float acc[12];
#pragma unroll
    for (int o = 0; o < 12; o++) acc[o] = b2[o];
    for (int ci = 0; ci < 48; ci++) {
        float zm = b2f(sZt[ci][t]);
        float z0 = b2f(sZt[ci][t + 1]);
        float zp = b2f(sZt[ci][t + 2]);
        const float* wp = w2 + ci * 3;   // uniform -> SGPR
#pragma unroll
        for (int o = 0; o < 12; o++)
            acc[o] += zm * wp[o * 144] + z0 * wp[o * 144 + 1] + zp * wp[o * 144 + 2];
    }
    const int l = l0 + t;
#pragma unroll
    for (int o = 0; o < 12; o++) {
        size_t idx = (size_t)b * 12288 + o * 1024 + l;
        out[idx] = acc[o] + skip[idx];
    }
}

// ------------------------------ launcher -----------------------------------

extern "C" void kernel_launch(void* const* d_in, const int* in_sizes, int n_in,
                              void* d_out, int out_size, void* d_ws, size_t ws_size,
                              hipStream_t stream)
{
    (void)in_sizes; (void)n_in; (void)out_size; (void)ws_size;
    const float* x      = (const float*)d_in[0];
    const float* ln_g   = (const float*)d_in[1];
    const float* ln_b   = (const float*)d_in[2];
    const float* fc1_w  = (const float*)d_in[3];
    const float* fc1_b  = (const float*)d_in[4];
    const float* fc2_w  = (const float*)d_in[5];
    const float* fc2_b  = (const float*)d_in[6];
    const float* conv1_w= (const float*)d_in[7];
    const float* conv1_b= (const float*)d_in[8];
    const float* conv2_w= (const float*)d_in[9];
    const float* conv2_b= (const float*)d_in[10];
    const float* xl_g   = (const float*)d_in[11];
    const float* xl_b   = (const float*)d_in[12];
    const float* Wg     = (const float*)d_in[13];
    const float* bg     = (const float*)d_in[14];
    const float* Rg     = (const float*)d_in[15];
    const float* gn_g   = (const float*)d_in[16];
    const float* gn_b   = (const float*)d_in[17];
    const float* upl_w  = (const float*)d_in[18];
    const float* upl_b  = (const float*)d_in[19];
    const float* upr_w  = (const float*)d_in[20];
    const float* upr_b  = (const float*)d_in[21];
    const float* down_w = (const float*)d_in[22];
    const float* down_b = (const float*)d_in[23];

    char* ws = (char*)d_ws;
    size_t off = 0;
    auto alloc = [&](size_t bytes) -> char* {
        char* p = ws + off;
        off = (off + bytes + 255) & ~(size_t)255;
        return p;
    };
    float* xn            = (float*)alloc(25165824);          // 6144x1024 f32
    float* xc            = (float*)alloc(25165824);
    float* x1            = (float*)alloc(25165824);
    unsigned short* xn2b = (unsigned short*)alloc(12582912); // 6144x1024 bf16
    unsigned short* gxb  = (unsigned short*)alloc(50331648); // 6144x4096 bf16
    unsigned short* hnb  = (unsigned short*)alloc(12582912);
    unsigned short* lrb  = (unsigned short*)alloc(25165824); // 6144x2048 bf16
    unsigned short* glrb = (unsigned short*)alloc(12582912);
    float* yb            = (float*)alloc(25165824);
    unsigned short* WgT  = (unsigned short*)alloc(8388608);  // 4096x1024 bf16
    unsigned short* WupT = (unsigned short*)alloc(4194304);  // 2048x1024 bf16
    unsigned short* WdT  = (unsigned short*)alloc(2097152);  // 1024x1024 bf16
    unsigned short* Rgb  = (unsigned short*)alloc(1048576);  // 8x512x128 bf16
    float* bup           = (float*)alloc(8192);              // 2048 f32
    // z (tail intermediate, 512x48x1024 bf16 = 50.3 MB) reuses gxb, which is
    // dead after slstm_rec_kernel.
    unsigned short* zb   = gxb;

    // weight prep
    transpose_bf16_k<<<dim3(128, 32), 256, 0, stream>>>(Wg, WgT, 1024, 4096);
    transpose_bf16_k<<<dim3(32, 32), 256, 0, stream>>>(upl_w, WupT, 1024, 1024);
    transpose_bf16_k<<<dim3(32, 32), 256, 0, stream>>>(upr_w, WupT + 1024 * 1024, 1024, 1024);
    transpose_bf16_k<<<dim3(32, 32), 256, 0, stream>>>(down_w, WdT, 1024, 1024);
    convert_bf16_k<<<2048, 256, 0, stream>>>(Rg, Rgb, 524288);
    cat_bias_k<<<8, 256, 0, stream>>>(upl_b, upr_b, bup);

    // main pipeline
    ln_kernel<0><<<6144, 256, 0, stream>>>(x, ln_g, ln_b, xn);
    fc_kernel<<<2048, 256, 0, stream>>>(xn, fc1_w, fc1_b, fc2_w, fc2_b, xc, x1);
    ln_kernel<1><<<6144, 256, 0, stream>>>(x1, xl_g, xl_b, xn2b);
    gemm_kernel<0><<<dim3(32, 48), 256, 0, stream>>>(
        xn2b, WgT, bg, gxb, 6144, 4096, 1024, nullptr, nullptr, nullptr);
    slstm_rec_kernel<<<dim3(8, 64), 256, 0, stream>>>(Rgb, gxb, gn_g, gn_b, hnb);
    gemm_kernel<0><<<dim3(16, 48), 256, 0, stream>>>(
        hnb, WupT, bup, lrb, 6144, 2048, 1024, nullptr, nullptr, nullptr);
    gate_kernel<<<24576, 256, 0, stream>>>(lrb, glrb);
    gemm_kernel<2><<<dim3(8, 48), 256, 0, stream>>>(
        glrb, WdT, down_b, yb, 6144, 1024, 1024, xc, x1, xn);
    tail_conv1_ln_kernel<<<dim3(512, 6), 256, 0, stream>>>(
        yb, conv1_w, conv1_b, ln_g, ln_b, zb);
    tail_conv2_kernel<<<dim3(512, 4), 256, 0, stream>>>(
        zb, xn, conv2_w, conv2_b, (float*)d_out);
}

// Round 3
// 676.381 us; speedup vs baseline: 2.8470x; 1.0954x over previous
//
#include <hip/hip_runtime.h>
#include <math.h>

// ---------------------------------------------------------------------------
// xLSTM decoder block, MI355X gfx950.
// Pipeline (all flat (b*12+ch)*1024+l layout):
//  prep:  weights -> bf16 (Wg/upl/upr/down transposed to [n][k], Rg straight)
//  ln1:   x -> xn (fp32)                           [skip]
//  fc:    xn -> xc (fp32), x1 (fp32)               (conv12->12 k3 + 1x1)
//  ln2:   x1 -> xn2 (bf16)
//  gemm0: xn2 @ WgT + bg -> gx (bf16, 6144x4096)
//  rec:   block-diagonal sLSTM per (head, 16 batches), Rg in LDS, fused GroupNorm
//         -> hn (bf16, 6144x1024)
//  gemm0: hn @ WupT + [upl_b|upr_b] -> lr (bf16, 6144x2048)
//  gate:  glr = gelu(left)*right (bf16)
//  gemm2: glr @ WdT + down_b ; epilogue y = silu(xc)*(acc+down_b+x1) + xn
//  tailA: conv1+gelu+LN(len) per (batch, 8-channel chunk) -> z bf16 (reuses gxb)
//  tailB: conv2(48->12)+skip per (batch, 256-pos tile)    -> d_out
// Round-3 changes:
//  * slstm_rec: 1024-thread blocks (16 waves -> 4/SIMD; was 1/SIMD at 11.6%
//    occupancy, VALUBusy 44%). 16 batches/block, q=2/thread, grid (8,32)=256
//    blocks = 1/CU. GroupNorm = one wave per batch via shuffle.
//  * GEMMs: global_load_lds width-16 staging (LDS dest byte = 16*t satisfies
//    the wave-uniform-base + lane*16 constraint).
// ---------------------------------------------------------------------------

typedef short short8_t __attribute__((ext_vector_type(8)));
typedef unsigned uint4_t __attribute__((ext_vector_type(4)));
typedef float floatx4 __attribute__((ext_vector_type(4)));
typedef float float2_t __attribute__((ext_vector_type(2)));
typedef float float4_t __attribute__((ext_vector_type(4)));

typedef unsigned int u32;
typedef const __attribute__((address_space(1))) u32 gu32;
typedef __attribute__((address_space(3))) u32 lu32;

static __device__ __forceinline__ float b2f(unsigned short u) {
    unsigned v = ((unsigned)u) << 16;
    return __builtin_bit_cast(float, v);
}
static __device__ __forceinline__ unsigned short f2b(float f) {
    unsigned u = __builtin_bit_cast(unsigned, f);
    u += 0x7FFFu + ((u >> 16) & 1u);   // RNE
    return (unsigned short)(u >> 16);
}
static __device__ __forceinline__ float2_t make2u(unsigned u) {
    float2_t r;
    r.x = __builtin_bit_cast(float, u << 16);
    r.y = __builtin_bit_cast(float, u & 0xFFFF0000u);
    return r;
}
static __device__ __forceinline__ float gelu_exact(float x) {
    return 0.5f * x * (1.f + erff(x * 0.70710678118654752f));
}

// --------------------------- weight prep ----------------------------------

__global__ __launch_bounds__(256) void transpose_bf16_k(
    const float* __restrict__ src, unsigned short* __restrict__ dst, int K, int N)
{   // dst[n*K+k] = bf16(src[k*N+n]); grid (N/32, K/32), block 256
    __shared__ unsigned short tl[32][33];
    const int n0 = blockIdx.x * 32, k0 = blockIdx.y * 32;
    const int tx = threadIdx.x & 31, ty = threadIdx.x >> 5; // ty 0..7
#pragma unroll
    for (int r = 0; r < 4; r++) {
        int k = ty + r * 8;
        tl[tx][k] = f2b(src[(size_t)(k0 + k) * N + n0 + tx]);
    }
    __syncthreads();
#pragma unroll
    for (int r = 0; r < 4; r++) {
        int n = ty * 4 + r;
        dst[(size_t)(n0 + n) * K + k0 + tx] = tl[n][tx];
    }
}

__global__ __launch_bounds__(256) void convert_bf16_k(
    const float* __restrict__ src, unsigned short* __restrict__ dst, int n)
{
    int gid = blockIdx.x * 256 + threadIdx.x;
    if (gid < n) dst[gid] = f2b(src[gid]);
}

__global__ __launch_bounds__(256) void cat_bias_k(
    const float* __restrict__ a, const float* __restrict__ b, float* __restrict__ o)
{
    int gid = blockIdx.x * 256 + threadIdx.x;   // 2048 total
    o[gid] = (gid < 1024) ? a[gid] : b[gid - 1024];
}

// ------------------------------ layernorm ----------------------------------

template <int BF16OUT>
__global__ __launch_bounds__(256) void ln_kernel(
    const float* __restrict__ in, const float* __restrict__ g,
    const float* __restrict__ be, void* __restrict__ outp)
{
    const int row = blockIdx.x;
    const float* xr = in + (size_t)row * 1024;
    const int t = threadIdx.x;
    float v[4];
    float s = 0.f, ss = 0.f;
#pragma unroll
    for (int u = 0; u < 4; u++) {
        float q = xr[t + u * 256];
        v[u] = q; s += q; ss += q * q;
    }
#pragma unroll
    for (int off = 32; off >= 1; off >>= 1) {
        s += __shfl_xor(s, off);
        ss += __shfl_xor(ss, off);
    }
    __shared__ float red[8];
    const int wv = t >> 6, la = t & 63;
    if (la == 0) { red[wv] = s; red[4 + wv] = ss; }
    __syncthreads();
    s = red[0] + red[1] + red[2] + red[3];
    ss = red[4] + red[5] + red[6] + red[7];
    float mu = s * (1.f / 1024.f);
    float var = ss * (1.f / 1024.f) - mu * mu;
    float rs = rsqrtf(var + 1e-5f);
#pragma unroll
    for (int u = 0; u < 4; u++) {
        int i = t + u * 256;
        float yv = (v[u] - mu) * rs * g[i] + be[i];
        if (BF16OUT)
            ((unsigned short*)outp)[(size_t)row * 1024 + i] = f2b(yv);
        else
            ((float*)outp)[(size_t)row * 1024 + i] = yv;
    }
}

// ---------------------- fc1 (conv k3) + fc2 (1x1) --------------------------

__global__ __launch_bounds__(256) void fc_kernel(
    const float* __restrict__ xn,
    const float* __restrict__ w1, const float* __restrict__ b1,
    const float* __restrict__ w2, const float* __restrict__ b2,
    float* __restrict__ xc, float* __restrict__ x1)
{
    const int t = threadIdx.x;
    const int gid = blockIdx.x * 256 + t;
    const int b = gid >> 10, l = gid & 1023;
    const float* xb = xn + (size_t)b * 12288;
    float inm[12], in0[12], inp[12];
#pragma unroll
    for (int ci = 0; ci < 12; ci++) {
        in0[ci] = xb[ci * 1024 + l];
        inm[ci] = (l > 0) ? xb[ci * 1024 + l - 1] : 0.f;
        inp[ci] = (l < 1023) ? xb[ci * 1024 + l + 1] : 0.f;
    }
    float xcv[12];
#pragma unroll
    for (int o = 0; o < 12; o++) {
        float a = b1[o];
#pragma unroll
        for (int ci = 0; ci < 12; ci++) {
            const float* wp = w1 + o * 36 + ci * 3;  // uniform -> s_load
            a += inm[ci] * wp[0] + in0[ci] * wp[1] + inp[ci] * wp[2];
        }
        xcv[o] = a;
        xc[(size_t)b * 12288 + o * 1024 + l] = a;
    }
#pragma unroll
    for (int o = 0; o < 12; o++) {
        float a = b2[o];
#pragma unroll
        for (int ci = 0; ci < 12; ci++) a += xcv[ci] * w2[o * 12 + ci];
        x1[(size_t)b * 12288 + o * 1024 + l] = a;
    }
}

// ------------------------------ bf16 GEMM ----------------------------------
// C[m][n] = sum_k A[m][k]*BT[n][k] + bias[n]; 128x128 tile, 4 waves 2x2,
// each wave 64x64 via 4x4 of mfma_f32_16x16x32_bf16. Staging via
// global_load_lds width-16: thread t's dest byte = 16*t.
// MODE 0: store bf16.  MODE 2: y = silu(xc)*(acc+bias+x1) + skip, store fp32.

template <int MODE>
__global__ __launch_bounds__(256) void gemm_kernel(
    const unsigned short* __restrict__ A, const unsigned short* __restrict__ BT,
    const float* __restrict__ bias, void* __restrict__ out,
    int M, int N, int K,
    const float* __restrict__ xc, const float* __restrict__ x1,
    const float* __restrict__ skip)
{
    __shared__ __align__(16) unsigned short sA[128 * 32];
    __shared__ __align__(16) unsigned short sB[128 * 32];
    const int t = threadIdx.x;
    const int m0 = blockIdx.y * 128;
    const int n0 = blockIdx.x * 128;
    const int w = t >> 6;
    const int lane = t & 63;
    const int wr = (w >> 1) * 64;
    const int wc = (w & 1) * 64;
    const int lrow = lane & 15;
    const int quad = lane >> 4;
    const int row_l = t >> 2;          // 0..63
    const int cs = (t & 3) * 8;        // 0,8,16,24

    const unsigned short* gA0 = A + (size_t)(m0 + row_l) * K + cs;
    const unsigned short* gA1 = A + (size_t)(m0 + row_l + 64) * K + cs;
    const unsigned short* gB0 = BT + (size_t)(n0 + row_l) * K + cs;
    const unsigned short* gB1 = BT + (size_t)(n0 + row_l + 64) * K + cs;
    unsigned short* lA0 = sA + w * 512;          // wave-uniform LDS bases
    unsigned short* lA1 = sA + 2048 + w * 512;
    unsigned short* lB0 = sB + w * 512;
    unsigned short* lB1 = sB + 2048 + w * 512;

    floatx4 acc[4][4];
#pragma unroll
    for (int i = 0; i < 4; i++)
#pragma unroll
        for (int j = 0; j < 4; j++) acc[i][j] = (floatx4)0.f;

    for (int k0 = 0; k0 < K; k0 += 32) {
        __syncthreads();
        __builtin_amdgcn_global_load_lds((gu32*)(gA0 + k0), (lu32*)lA0, 16, 0, 0);
        __builtin_amdgcn_global_load_lds((gu32*)(gA1 + k0), (lu32*)lA1, 16, 0, 0);
        __builtin_amdgcn_global_load_lds((gu32*)(gB0 + k0), (lu32*)lB0, 16, 0, 0);
        __builtin_amdgcn_global_load_lds((gu32*)(gB1 + k0), (lu32*)lB1, 16, 0, 0);
        __syncthreads();
        short8_t af[4], bfr[4];
#pragma unroll
        for (int i = 0; i < 4; i++) {
            af[i] = *(const short8_t*)(sA + (wr + i * 16 + lrow) * 32 + quad * 8);
            bfr[i] = *(const short8_t*)(sB + (wc + i * 16 + lrow) * 32 + quad * 8);
        }
#pragma unroll
        for (int i = 0; i < 4; i++)
#pragma unroll
            for (int j = 0; j < 4; j++)
                acc[i][j] = __builtin_amdgcn_mfma_f32_16x16x32_bf16(
                    af[i], bfr[j], acc[i][j], 0, 0, 0);
    }

#pragma unroll
    for (int i = 0; i < 4; i++) {
#pragma unroll
        for (int j = 0; j < 4; j++) {
#pragma unroll
            for (int r = 0; r < 4; r++) {
                const int gm = m0 + wr + i * 16 + quad * 4 + r;
                const int gn = n0 + wc + j * 16 + lrow;
                const size_t idx = (size_t)gm * N + gn;
                float v = acc[i][j][r] + bias[gn];
                if (MODE == 0) {
                    ((unsigned short*)out)[idx] = f2b(v);
                } else {
                    float xcv = xc[idx];
                    float sig = xcv / (1.f + __expf(-xcv));
                    ((float*)out)[idx] = sig * (v + x1[idx]) + skip[idx];
                }
            }
        }
    }
}

// ------------------- sLSTM recurrence + GroupNorm (fused) ------------------
// grid (NH=8, B/16=32) = 256 blocks (1/CU), block 1024 (16 waves -> 4/SIMD).
// Rg[head] bf16 in LDS (136 KB padded); sH 16 batches x 128 fp32 (8 KB).
// thread t: hs = t&127, group g = t>>7 handles batches 2g, 2g+1.
// GroupNorm phase: wave (t>>6) = batch, pure shuffle reduce.

#define RSTRIDE 136

__global__ __launch_bounds__(1024) void slstm_rec_kernel(
    const unsigned short* __restrict__ Rgb,   // [8][512][128] bf16
    const unsigned short* __restrict__ gxb,   // [B][12][4096] bf16
    const float* __restrict__ gn_g, const float* __restrict__ gn_b,
    unsigned short* __restrict__ hnb)         // [B][12][1024] bf16
{
    __shared__ __align__(16) unsigned short sR[512 * RSTRIDE];  // 136 KB
    __shared__ __align__(16) float sH[16][128];                 // 8 KB
    const int head = blockIdx.x;
    const int b0 = blockIdx.y * 16;
    const int t = threadIdx.x;
    const unsigned short* Rh = Rgb + (size_t)head * 65536;
    for (int i = t; i < 512 * 16; i += 1024) {
        int g = i >> 4, c = (i & 15) * 8;
        *(short8_t*)(sR + g * RSTRIDE + c) = *(const short8_t*)(Rh + g * 128 + c);
    }
    for (int i = t; i < 2048; i += 1024) (&sH[0][0])[i] = 0.f;
    __syncthreads();

    const int hs = t & 127;
    const int grp = t >> 7;        // 0..7
    const int bb0 = grp * 2;       // local batches bb0, bb0+1
    float cst[2], nst[2], mst[2];
#pragma unroll
    for (int q = 0; q < 2; q++) { cst[q] = 0.f; nst[q] = 0.f; mst[q] = 0.f; }

    const unsigned short* rz = sR + (size_t)hs * RSTRIDE;
    const unsigned short* rri = sR + (size_t)(128 + hs) * RSTRIDE;
    const unsigned short* rrf = sR + (size_t)(256 + hs) * RSTRIDE;
    const unsigned short* rro = sR + (size_t)(384 + hs) * RSTRIDE;

    // GroupNorm mapping: one wave per batch
    const int gnb = t >> 6;        // 0..15 local batch
    const int la = t & 63;
    const float gg0 = gn_g[head * 128 + la];
    const float gg1 = gn_g[head * 128 + la + 64];
    const float gb0 = gn_b[head * 128 + la];
    const float gb1 = gn_b[head * 128 + la + 64];

    for (int step = 0; step < 12; step++) {
        // prefetch gate pre-activations (global, overlaps the dot loop)
        float gpre[2][4];
#pragma unroll
        for (int q = 0; q < 2; q++) {
            const unsigned short* gp =
                gxb + ((size_t)(b0 + bb0 + q) * 12 + step) * 4096 + head * 512 + hs;
            gpre[q][0] = b2f(gp[0]);
            gpre[q][1] = b2f(gp[128]);
            gpre[q][2] = b2f(gp[256]);
            gpre[q][3] = b2f(gp[384]);
        }
        float2_t az[2], aiv[2], afv[2], aov[2];
#pragma unroll
        for (int q = 0; q < 2; q++) {
            az[q] = (float2_t)0.f; aiv[q] = (float2_t)0.f;
            afv[q] = (float2_t)0.f; aov[q] = (float2_t)0.f;
        }
#pragma unroll 4
        for (int k = 0; k < 128; k += 8) {
            uint4_t vz = *(const uint4_t*)(rz + k);
            uint4_t vi = *(const uint4_t*)(rri + k);
            uint4_t vf = *(const uint4_t*)(rrf + k);
            uint4_t vo = *(const uint4_t*)(rro + k);
            float2_t fz[4], fi[4], ff[4], fo[4];
#pragma unroll
            for (int p = 0; p < 4; p++) {
                fz[p] = make2u(vz[p]); fi[p] = make2u(vi[p]);
                ff[p] = make2u(vf[p]); fo[p] = make2u(vo[p]);
            }
#pragma unroll
            for (int q = 0; q < 2; q++) {
                const float* hb = &sH[bb0 + q][k];
                float2_t h0 = *(const float2_t*)(hb);
                float2_t h1 = *(const float2_t*)(hb + 2);
                float2_t h2 = *(const float2_t*)(hb + 4);
                float2_t h3 = *(const float2_t*)(hb + 6);
                az[q] += fz[0] * h0 + fz[1] * h1 + fz[2] * h2 + fz[3] * h3;
                aiv[q] += fi[0] * h0 + fi[1] * h1 + fi[2] * h2 + fi[3] * h3;
                afv[q] += ff[0] * h0 + ff[1] * h1 + ff[2] * h2 + ff[3] * h3;
                aov[q] += fo[0] * h0 + fo[1] * h1 + fo[2] * h2 + fo[3] * h3;
            }
        }
        float hv[2];
#pragma unroll
        for (int q = 0; q < 2; q++) {
            float zp = gpre[q][0] + az[q].x + az[q].y;
            float ip = gpre[q][1] + aiv[q].x + aiv[q].y;
            float fp = gpre[q][2] + afv[q].x + afv[q].y;
            float op = gpre[q][3] + aov[q].x + aov[q].y;
            float e2 = __expf(2.f * zp);
            float z = (e2 - 1.f) / (e2 + 1.f);
            float o = 1.f / (1.f + __expf(-op));
            float mn = fmaxf(fp + mst[q], ip);
            float ie = __expf(ip - mn);
            float fe = __expf(fp + mst[q] - mn);
            cst[q] = fe * cst[q] + ie * z;
            nst[q] = fe * nst[q] + ie;
            mst[q] = mn;
            hv[q] = o * (cst[q] / nst[q]);
        }
        __syncthreads();   // prior-step sH fully consumed
        sH[bb0][hs] = hv[0];
        sH[bb0 + 1][hs] = hv[1];
        __syncthreads();   // sH complete for GN + next step
        {
            float v0 = sH[gnb][la];
            float v1 = sH[gnb][la + 64];
            float s = v0 + v1;
            float ss = v0 * v0 + v1 * v1;
#pragma unroll
            for (int off = 32; off >= 1; off >>= 1) {
                s += __shfl_xor(s, off);
                ss += __shfl_xor(ss, off);
            }
            float mu = s * (1.f / 128.f);
            float var = ss * (1.f / 128.f) - mu * mu;
            float rs = rsqrtf(var + 1e-5f);
            size_t base = ((size_t)(b0 + gnb) * 12 + step) * 1024 + head * 128;
            hnb[base + la] = f2b((v0 - mu) * rs * gg0 + gb0);
            hnb[base + la + 64] = f2b((v1 - mu) * rs * gg1 + gb1);
        }
    }
}

// ------------------------------ gate kernel --------------------------------

__global__ __launch_bounds__(256) void gate_kernel(
    const unsigned short* __restrict__ lr, unsigned short* __restrict__ glr)
{
    size_t gid = (size_t)blockIdx.x * 256 + threadIdx.x;  // 6144*1024
    size_t m = gid >> 10;
    int j = (int)(gid & 1023);
    float lf = b2f(lr[m * 2048 + j]);
    float rt = b2f(lr[m * 2048 + 1024 + j]);
    glr[gid] = f2b(gelu_exact(lf) * rt);
}

// ------------------ tail A: conv1(12->48)+gelu+LN(length) ------------------
// grid (512 batches, 6 chunks of 8 out-channels), block 256.
// Values in registers, weights via wave-uniform s_load. Spill-free by design.

__global__ __launch_bounds__(256) void tail_conv1_ln_kernel(
    const float* __restrict__ y, const float* __restrict__ w1,
    const float* __restrict__ b1, const float* __restrict__ lng,
    const float* __restrict__ lnb, unsigned short* __restrict__ z)
{
    __shared__ float sX[12 * 1024];          // 48 KB
    __shared__ unsigned short sZ[8][1024];   // 16 KB
    __shared__ float sred[2][8][4];
    const int b = blockIdx.x;
    const int o0 = blockIdx.y * 8;
    const int t = threadIdx.x;

    const float4_t* srcv = (const float4_t*)(y + (size_t)b * 12288);
    float4_t* dstv = (float4_t*)sX;
    for (int i = t; i < 3072; i += 256) dstv[i] = srcv[i];
    __syncthreads();

    float s[8], ss[8];
#pragma unroll
    for (int o = 0; o < 8; o++) { s[o] = 0.f; ss[o] = 0.f; }

    for (int p = 0; p < 4; p++) {
        const int l = t + p * 256;
        float vm[12], v0[12], vp[12];
#pragma unroll
        for (int ci = 0; ci < 12; ci++) {
            v0[ci] = sX[ci * 1024 + l];
            vm[ci] = (l > 0) ? sX[ci * 1024 + l - 1] : 0.f;
            vp[ci] = (l < 1023) ? sX[ci * 1024 + l + 1] : 0.f;
        }
#pragma unroll
        for (int o = 0; o < 8; o++) {
            const float* wp = w1 + (o0 + o) * 36;   // uniform -> SGPR
            float a = b1[o0 + o];
#pragma unroll
            for (int ci = 0; ci < 12; ci++)
                a += vm[ci] * wp[ci * 3] + v0[ci] * wp[ci * 3 + 1] + vp[ci] * wp[ci * 3 + 2];
            float g = gelu_exact(a);
            s[o] += g; ss[o] += g * g;
            sZ[o][l] = f2b(g);
        }
    }
    // block reduction of per-row stats
    const int wv = t >> 6, la = t & 63;
#pragma unroll
    for (int o = 0; o < 8; o++) {
        float a = s[o], q = ss[o];
#pragma unroll
        for (int off = 32; off >= 1; off >>= 1) {
            a += __shfl_xor(a, off);
            q += __shfl_xor(q, off);
        }
        if (la == 0) { sred[0][o][wv] = a; sred[1][o][wv] = q; }
    }
    __syncthreads();
    float mu[8], rs[8];
#pragma unroll
    for (int o = 0; o < 8; o++) {
        float S = sred[0][o][0] + sred[0][o][1] + sred[0][o][2] + sred[0][o][3];
        float Q = sred[1][o][0] + sred[1][o][1] + sred[1][o][2] + sred[1][o][3];
        float m = S * (1.f / 1024.f);
        float var = Q * (1.f / 1024.f) - m * m;
        mu[o] = m;
        rs[o] = rsqrtf(var + 1e-5f);
    }
    for (int p = 0; p < 4; p++) {
        const int l = t + p * 256;
        const float lg = lng[l], lb = lnb[l];
#pragma unroll
        for (int o = 0; o < 8; o++) {
            float v = b2f(sZ[o][l]);
            z[((size_t)b * 48 + o0 + o) * 1024 + l] = f2b((v - mu[o]) * rs[o] * lg + lb);
        }
    }
}

// -------------------- tail B: conv2(48->12) + skip -------------------------
// grid (512 batches, 4 tiles of 256 positions), block 256.

__global__ __launch_bounds__(256) void tail_conv2_kernel(
    const unsigned short* __restrict__ z, const float* __restrict__ skip,
    const float* __restrict__ w2, const float* __restrict__ b2,
    float* __restrict__ out)
{
    __shared__ unsigned short sZt[48][258];
    const int b = blockIdx.x;
    const int l0 = blockIdx.y * 256;
    const int t = threadIdx.x;
    const unsigned short* zb = z + (size_t)b * 49152;
    for (int ci = 0; ci < 48; ci++) {
        int l = l0 - 1 + t;
        sZt[ci][t] = (l >= 0 && l < 1024) ? zb[ci * 1024 + l] : (unsigned short)0;
        if (t < 2) {
            int l2 = l0 - 1 + 256 + t;
            sZt[ci][256 + t] = (l2 >= 0 && l2 < 1024) ? zb[ci * 1024 + l2] : (unsigned short)0;
        }
    }
    __syncthreads();
    float acc[12];
#pragma unroll
    for (int o = 0; o < 12; o++) acc[o] = b2[o];
    for (int ci = 0; ci < 48; ci++) {
        float zm = b2f(sZt[ci][t]);
        float z0 = b2f(sZt[ci][t + 1]);
        float zp = b2f(sZt[ci][t + 2]);
        const float* wp = w2 + ci * 3;   // uniform -> SGPR
#pragma unroll
        for (int o = 0; o < 12; o++)
            acc[o] += zm * wp[o * 144] + z0 * wp[o * 144 + 1] + zp * wp[o * 144 + 2];
    }
    const int l = l0 + t;
#pragma unroll
    for (int o = 0; o < 12; o++) {
        size_t idx = (size_t)b * 12288 + o * 1024 + l;
        out[idx] = acc[o] + skip[idx];
    }
}

// ------------------------------ launcher -----------------------------------

extern "C" void kernel_launch(void* const* d_in, const int* in_sizes, int n_in,
                              void* d_out, int out_size, void* d_ws, size_t ws_size,
                              hipStream_t stream)
{
    (void)in_sizes; (void)n_in; (void)out_size; (void)ws_size;
    const float* x      = (const float*)d_in[0];
    const float* ln_g   = (const float*)d_in[1];
    const float* ln_b   = (const float*)d_in[2];
    const float* fc1_w  = (const float*)d_in[3];
    const float* fc1_b  = (const float*)d_in[4];
    const float* fc2_w  = (const float*)d_in[5];
    const float* fc2_b  = (const float*)d_in[6];
    const float* conv1_w= (const float*)d_in[7];
    const float* conv1_b= (const float*)d_in[8];
    const float* conv2_w= (const float*)d_in[9];
    const float* conv2_b= (const float*)d_in[10];
    const float* xl_g   = (const float*)d_in[11];
    const float* xl_b   = (const float*)d_in[12];
    const float* Wg     = (const float*)d_in[13];
    const float* bg     = (const float*)d_in[14];
    const float* Rg     = (const float*)d_in[15];
    const float* gn_g   = (const float*)d_in[16];
    const float* gn_b   = (const float*)d_in[17];
    const float* upl_w  = (const float*)d_in[18];
    const float* upl_b  = (const float*)d_in[19];
    const float* upr_w  = (const float*)d_in[20];
    const float* upr_b  = (const float*)d_in[21];
    const float* down_w = (const float*)d_in[22];
    const float* down_b = (const float*)d_in[23];

    char* ws = (char*)d_ws;
    size_t off = 0;
    auto alloc = [&](size_t bytes) -> char* {
        char* p = ws + off;
        off = (off + bytes + 255) & ~(size_t)255;
        return p;
    };
    float* xn            = (float*)alloc(25165824);          // 6144x1024 f32
    float* xc            = (float*)alloc(25165824);
    float* x1            = (float*)alloc(25165824);
    unsigned short* xn2b = (unsigned short*)alloc(12582912); // 6144x1024 bf16
    unsigned short* gxb  = (unsigned short*)alloc(50331648); // 6144x4096 bf16
    unsigned short* hnb  = (unsigned short*)alloc(12582912);
    unsigned short* lrb  = (unsigned short*)alloc(25165824); // 6144x2048 bf16
    unsigned short* glrb = (unsigned short*)alloc(12582912);
    float* yb            = (float*)alloc(25165824);
    unsigned short* WgT  = (unsigned short*)alloc(8388608);  // 4096x1024 bf16
    unsigned short* WupT = (unsigned short*)alloc(4194304);  // 2048x1024 bf16
    unsigned short* WdT  = (unsigned short*)alloc(2097152);  // 1024x1024 bf16
    unsigned short* Rgb  = (unsigned short*)alloc(1048576);  // 8x512x128 bf16
    float* bup           = (float*)alloc(8192);              // 2048 f32
    // z (tail intermediate, 512x48x1024 bf16 = 50.3 MB) reuses gxb, which is
    // dead after slstm_rec_kernel.
    unsigned short* zb   = gxb;

    // weight prep
    transpose_bf16_k<<<dim3(128, 32), 256, 0, stream>>>(Wg, WgT, 1024, 4096);
    transpose_bf16_k<<<dim3(32, 32), 256, 0, stream>>>(upl_w, WupT, 1024, 1024);
    transpose_bf16_k<<<dim3(32, 32), 256, 0, stream>>>(upr_w, WupT + 1024 * 1024, 1024, 1024);
    transpose_bf16_k<<<dim3(32, 32), 256, 0, stream>>>(down_w, WdT, 1024, 1024);
    convert_bf16_k<<<2048, 256, 0, stream>>>(Rg, Rgb, 524288);
    cat_bias_k<<<8, 256, 0, stream>>>(upl_b, upr_b, bup);

    // main pipeline
    ln_kernel<0><<<6144, 256, 0, stream>>>(x, ln_g, ln_b, xn);
    fc_kernel<<<2048, 256, 0, stream>>>(xn, fc1_w, fc1_b, fc2_w, fc2_b, xc, x1);
    ln_kernel<1><<<6144, 256, 0, stream>>>(x1, xl_g, xl_b, xn2b);
    gemm_kernel<0><<<dim3(32, 48), 256, 0, stream>>>(
        xn2b, WgT, bg, gxb, 6144, 4096, 1024, nullptr, nullptr, nullptr);
    slstm_rec_kernel<<<dim3(8, 32), 1024, 0, stream>>>(Rgb, gxb, gn_g, gn_b, hnb);
    gemm_kernel<0><<<dim3(16, 48), 256, 0, stream>>>(
        hnb, WupT, bup, lrb, 6144, 2048, 1024, nullptr, nullptr, nullptr);
    gate_kernel<<<24576, 256, 0, stream>>>(lrb, glrb);
    gemm_kernel<2><<<dim3(8, 48), 256, 0, stream>>>(
        glrb, WdT, down_b, yb, 6144, 1024, 1024, xc, x1, xn);
    tail_conv1_ln_kernel<<<dim3(512, 6), 256, 0, stream>>>(
        yb, conv1_w, conv1_b, ln_g, ln_b, zb);
    tail_conv2_kernel<<<dim3(512, 4), 256, 0, stream>>>(
        zb, xn, conv2_w, conv2_b, (float*)d_out);
}

// Round 4
// 568.692 us; speedup vs baseline: 3.3861x; 1.1894x over previous
//
#include <hip/hip_runtime.h>
#include <math.h>

// ---------------------------------------------------------------------------
// xLSTM decoder block, MI355X gfx950.
// Pipeline (all flat (b*12+ch)*1024+l layout):
//  prep:  weights -> bf16 (Wg/upl/upr/down transposed to [n][k])
//  ln1:   x -> xn (fp32)                           [skip]
//  fc:    xn -> xc (fp32), x1 (fp32)               (conv12->12 k3 + 1x1)
//  ln2:   x1 -> xn2 (bf16)
//  gemm0: xn2 @ WgT + bg -> gx (bf16, 6144x4096)
//  rec:   MFMA sLSTM per (head, 16 batches): R^T in VGPR B-fragments,
//         h->rec via mfma 16x16x32, state+GroupNorm in-wave -> hn (bf16)
//  gemm0: hn @ WupT + [upl_b|upr_b] -> lr (bf16, 6144x2048)
//  gate:  glr = gelu(left)*right (bf16)
//  gemm2: glr @ WdT + down_b ; epilogue y = silu(xc)*(acc+down_b+x1) + xn
//  tailA: conv1+gelu+LN(len) per (batch, 8-channel chunk) -> z bf16 (reuses gxb)
//  tailB: conv2(48->12)+skip per (batch, 256-pos tile)    -> d_out
// Round-4 change: slstm_rec was LDS-BW-bound (25 MB LDS reads/CU: R re-read
// from LDS every step). Now R is held in VGPRs (32/wave) and the dot is a
// 16x512x128 MFMA per step; LDS traffic ~0.9 MB/CU. GroupNorm via in-wave
// shuffle (wave=batch).
// ---------------------------------------------------------------------------

typedef short short8_t __attribute__((ext_vector_type(8)));
typedef float floatx4 __attribute__((ext_vector_type(4)));
typedef float float4_t __attribute__((ext_vector_type(4)));

typedef unsigned int u32;
typedef const __attribute__((address_space(1))) u32 gu32;
typedef __attribute__((address_space(3))) u32 lu32;

static __device__ __forceinline__ float b2f(unsigned short u) {
    unsigned v = ((unsigned)u) << 16;
    return __builtin_bit_cast(float, v);
}
static __device__ __forceinline__ unsigned short f2b(float f) {
    unsigned u = __builtin_bit_cast(unsigned, f);
    u += 0x7FFFu + ((u >> 16) & 1u);   // RNE
    return (unsigned short)(u >> 16);
}
static __device__ __forceinline__ float gelu_exact(float x) {
    return 0.5f * x * (1.f + erff(x * 0.70710678118654752f));
}

// --------------------------- weight prep ----------------------------------

__global__ __launch_bounds__(256) void transpose_bf16_k(
    const float* __restrict__ src, unsigned short* __restrict__ dst, int K, int N)
{   // dst[n*K+k] = bf16(src[k*N+n]); grid (N/32, K/32), block 256
    __shared__ unsigned short tl[32][33];
    const int n0 = blockIdx.x * 32, k0 = blockIdx.y * 32;
    const int tx = threadIdx.x & 31, ty = threadIdx.x >> 5; // ty 0..7
#pragma unroll
    for (int r = 0; r < 4; r++) {
        int k = ty + r * 8;
        tl[tx][k] = f2b(src[(size_t)(k0 + k) * N + n0 + tx]);
    }
    __syncthreads();
#pragma unroll
    for (int r = 0; r < 4; r++) {
        int n = ty * 4 + r;
        dst[(size_t)(n0 + n) * K + k0 + tx] = tl[n][tx];
    }
}

__global__ __launch_bounds__(256) void cat_bias_k(
    const float* __restrict__ a, const float* __restrict__ b, float* __restrict__ o)
{
    int gid = blockIdx.x * 256 + threadIdx.x;   // 2048 total
    o[gid] = (gid < 1024) ? a[gid] : b[gid - 1024];
}

// ------------------------------ layernorm ----------------------------------

template <int BF16OUT>
__global__ __launch_bounds__(256) void ln_kernel(
    const float* __restrict__ in, const float* __restrict__ g,
    const float* __restrict__ be, void* __restrict__ outp)
{
    const int row = blockIdx.x;
    const float* xr = in + (size_t)row * 1024;
    const int t = threadIdx.x;
    float v[4];
    float s = 0.f, ss = 0.f;
#pragma unroll
    for (int u = 0; u < 4; u++) {
        float q = xr[t + u * 256];
        v[u] = q; s += q; ss += q * q;
    }
#pragma unroll
    for (int off = 32; off >= 1; off >>= 1) {
        s += __shfl_xor(s, off);
        ss += __shfl_xor(ss, off);
    }
    __shared__ float red[8];
    const int wv = t >> 6, la = t & 63;
    if (la == 0) { red[wv] = s; red[4 + wv] = ss; }
    __syncthreads();
    s = red[0] + red[1] + red[2] + red[3];
    ss = red[4] + red[5] + red[6] + red[7];
    float mu = s * (1.f / 1024.f);
    float var = ss * (1.f / 1024.f) - mu * mu;
    float rs = rsqrtf(var + 1e-5f);
#pragma unroll
    for (int u = 0; u < 4; u++) {
        int i = t + u * 256;
        float yv = (v[u] - mu) * rs * g[i] + be[i];
        if (BF16OUT)
            ((unsigned short*)outp)[(size_t)row * 1024 + i] = f2b(yv);
        else
            ((float*)outp)[(size_t)row * 1024 + i] = yv;
    }
}

// ---------------------- fc1 (conv k3) + fc2 (1x1) --------------------------

__global__ __launch_bounds__(256) void fc_kernel(
    const float* __restrict__ xn,
    const float* __restrict__ w1, const float* __restrict__ b1,
    const float* __restrict__ w2, const float* __restrict__ b2,
    float* __restrict__ xc, float* __restrict__ x1)
{
    const int t = threadIdx.x;
    const int gid = blockIdx.x * 256 + t;
    const int b = gid >> 10, l = gid & 1023;
    const float* xb = xn + (size_t)b * 12288;
    float inm[12], in0[12], inp[12];
#pragma unroll
    for (int ci = 0; ci < 12; ci++) {
        in0[ci] = xb[ci * 1024 + l];
        inm[ci] = (l > 0) ? xb[ci * 1024 + l - 1] : 0.f;
        inp[ci] = (l < 1023) ? xb[ci * 1024 + l + 1] : 0.f;
    }
    float xcv[12];
#pragma unroll
    for (int o = 0; o < 12; o++) {
        float a = b1[o];
#pragma unroll
        for (int ci = 0; ci < 12; ci++) {
            const float* wp = w1 + o * 36 + ci * 3;  // uniform -> s_load
            a += inm[ci] * wp[0] + in0[ci] * wp[1] + inp[ci] * wp[2];
        }
        xcv[o] = a;
        xc[(size_t)b * 12288 + o * 1024 + l] = a;
    }
#pragma unroll
    for (int o = 0; o < 12; o++) {
        float a = b2[o];
#pragma unroll
        for (int ci = 0; ci < 12; ci++) a += xcv[ci] * w2[o * 12 + ci];
        x1[(size_t)b * 12288 + o * 1024 + l] = a;
    }
}

// ------------------------------ bf16 GEMM ----------------------------------
// C[m][n] = sum_k A[m][k]*BT[n][k] + bias[n]; 128x128 tile, 4 waves 2x2,
// each wave 64x64 via 4x4 of mfma_f32_16x16x32_bf16. Staging via
// global_load_lds width-16: thread t's dest byte = 16*t.
// MODE 0: store bf16.  MODE 2: y = silu(xc)*(acc+bias+x1) + skip, store fp32.

template <int MODE>
__global__ __launch_bounds__(256) void gemm_kernel(
    const unsigned short* __restrict__ A, const unsigned short* __restrict__ BT,
    const float* __restrict__ bias, void* __restrict__ out,
    int M, int N, int K,
    const float* __restrict__ xc, const float* __restrict__ x1,
    const float* __restrict__ skip)
{
    __shared__ __align__(16) unsigned short sA[128 * 32];
    __shared__ __align__(16) unsigned short sB[128 * 32];
    const int t = threadIdx.x;
    const int m0 = blockIdx.y * 128;
    const int n0 = blockIdx.x * 128;
    const int w = t >> 6;
    const int lane = t & 63;
    const int wr = (w >> 1) * 64;
    const int wc = (w & 1) * 64;
    const int lrow = lane & 15;
    const int quad = lane >> 4;
    const int row_l = t >> 2;          // 0..63
    const int cs = (t & 3) * 8;        // 0,8,16,24

    const unsigned short* gA0 = A + (size_t)(m0 + row_l) * K + cs;
    const unsigned short* gA1 = A + (size_t)(m0 + row_l + 64) * K + cs;
    const unsigned short* gB0 = BT + (size_t)(n0 + row_l) * K + cs;
    const unsigned short* gB1 = BT + (size_t)(n0 + row_l + 64) * K + cs;
    unsigned short* lA0 = sA + w * 512;          // wave-uniform LDS bases
    unsigned short* lA1 = sA + 2048 + w * 512;
    unsigned short* lB0 = sB + w * 512;
    unsigned short* lB1 = sB + 2048 + w * 512;

    floatx4 acc[4][4];
#pragma unroll
    for (int i = 0; i < 4; i++)
#pragma unroll
        for (int j = 0; j < 4; j++) acc[i][j] = (floatx4)0.f;

    for (int k0 = 0; k0 < K; k0 += 32) {
        __syncthreads();
        __builtin_amdgcn_global_load_lds((gu32*)(gA0 + k0), (lu32*)lA0, 16, 0, 0);
        __builtin_amdgcn_global_load_lds((gu32*)(gA1 + k0), (lu32*)lA1, 16, 0, 0);
        __builtin_amdgcn_global_load_lds((gu32*)(gB0 + k0), (lu32*)lB0, 16, 0, 0);
        __builtin_amdgcn_global_load_lds((gu32*)(gB1 + k0), (lu32*)lB1, 16, 0, 0);
        __syncthreads();
        short8_t af[4], bfr[4];
#pragma unroll
        for (int i = 0; i < 4; i++) {
            af[i] = *(const short8_t*)(sA + (wr + i * 16 + lrow) * 32 + quad * 8);
            bfr[i] = *(const short8_t*)(sB + (wc + i * 16 + lrow) * 32 + quad * 8);
        }
#pragma unroll
        for (int i = 0; i < 4; i++)
#pragma unroll
            for (int j = 0; j < 4; j++)
                acc[i][j] = __builtin_amdgcn_mfma_f32_16x16x32_bf16(
                    af[i], bfr[j], acc[i][j], 0, 0, 0);
    }

#pragma unroll
    for (int i = 0; i < 4; i++) {
#pragma unroll
        for (int j = 0; j < 4; j++) {
#pragma unroll
            for (int r = 0; r < 4; r++) {
                const int gm = m0 + wr + i * 16 + quad * 4 + r;
                const int gn = n0 + wc + j * 16 + lrow;
                const size_t idx = (size_t)gm * N + gn;
                float v = acc[i][j][r] + bias[gn];
                if (MODE == 0) {
                    ((unsigned short*)out)[idx] = f2b(v);
                } else {
                    float xcv = xc[idx];
                    float sig = xcv / (1.f + __expf(-xcv));
                    ((float*)out)[idx] = sig * (v + x1[idx]) + skip[idx];
                }
            }
        }
    }
}

// ------------------- sLSTM recurrence + GroupNorm (MFMA) -------------------
// grid (NH=8, B/16=32) = 256 blocks (1/CU), block 1024 (16 waves, 4/SIMD).
// Per step: rec(16x512) = h(16x128) @ Rg[head]^T(128x512) via 16x16x32 MFMA.
// Wave w owns gate cols [32w,32w+32): B-fragments (32 VGPR) held for all steps.
// State phase: wave = local batch, lane la owns hs=la and hs=la+64; GroupNorm
// is an in-wave shuffle reduction. h round-trips through LDS as bf16 (A frags).

#define RECP 516   // f32 row stride for sRec (2-way bank aliasing only)
#define HBP  136   // bf16 row stride for sHb

__global__ __launch_bounds__(1024, 4) void slstm_rec_kernel(
    const float* __restrict__ Rg,             // [8][512][128] f32
    const unsigned short* __restrict__ gxb,   // [B][12][4096] bf16
    const float* __restrict__ gn_g, const float* __restrict__ gn_b,
    unsigned short* __restrict__ hnb)         // [B][12][1024] bf16
{
    __shared__ __align__(16) float sRec[16 * RECP];           // 33.0 KB
    __shared__ __align__(16) unsigned short sHb[16 * HBP];    // 4.4 KB
    const int head = blockIdx.x;
    const int b0 = blockIdx.y * 16;
    const int t = threadIdx.x;
    const int w = t >> 6;          // wave id = MFMA col-slice = state batch
    const int lane = t & 63;
    const int quad = lane >> 4;
    const int l16 = lane & 15;

    // ---- B fragments: Bf[jt][kk] holds Rg[head][32w+16jt+l16][32kk+8quad+j]
    short8_t Bf[2][4];
    {
        const float* Rh = Rg + (size_t)head * 65536;
#pragma unroll
        for (int jt = 0; jt < 2; jt++)
#pragma unroll
            for (int kk = 0; kk < 4; kk++) {
                const float* src =
                    Rh + (size_t)(w * 32 + jt * 16 + l16) * 128 + kk * 32 + quad * 8;
                short8_t v;
#pragma unroll
                for (int j = 0; j < 8; j++) v[j] = (short)f2b(src[j]);
                Bf[jt][kk] = v;
            }
    }

    for (int i = t; i < 16 * HBP; i += 1024) sHb[i] = 0;

    // state-role constants (wave = local batch, lane la -> hs = la, la+64)
    const int la = lane;
    float c0 = 0.f, n0s = 0.f, m0 = 0.f;
    float c1 = 0.f, n1s = 0.f, m1 = 0.f;
    const float gg0 = gn_g[head * 128 + la];
    const float gg1 = gn_g[head * 128 + la + 64];
    const float gb0 = gn_b[head * 128 + la];
    const float gb1 = gn_b[head * 128 + la + 64];

    __syncthreads();

    for (int step = 0; step < 12; step++) {
        // gx pre-activation loads (global; overlap with MFMA phase)
        const unsigned short* gp =
            gxb + ((size_t)(b0 + w) * 12 + step) * 4096 + head * 512;
        float gz0 = b2f(gp[la]),       gz1 = b2f(gp[64 + la]);
        float gi0 = b2f(gp[128 + la]), gi1 = b2f(gp[192 + la]);
        float gf0 = b2f(gp[256 + la]), gf1 = b2f(gp[320 + la]);
        float go0 = b2f(gp[384 + la]), go1 = b2f(gp[448 + la]);

        // MFMA phase: rec = h @ R^T for this wave's 32 cols
        short8_t Af[4];
#pragma unroll
        for (int kk = 0; kk < 4; kk++)
            Af[kk] = *(const short8_t*)(sHb + l16 * HBP + kk * 32 + quad * 8);
        floatx4 D0 = (floatx4)0.f, D1 = (floatx4)0.f;
#pragma unroll
        for (int kk = 0; kk < 4; kk++) {
            D0 = __builtin_amdgcn_mfma_f32_16x16x32_bf16(Af[kk], Bf[0][kk], D0, 0, 0, 0);
            D1 = __builtin_amdgcn_mfma_f32_16x16x32_bf16(Af[kk], Bf[1][kk], D1, 0, 0, 0);
        }
#pragma unroll
        for (int r = 0; r < 4; r++) {
            sRec[(quad * 4 + r) * RECP + w * 32 + l16] = D0[r];
            sRec[(quad * 4 + r) * RECP + w * 32 + 16 + l16] = D1[r];
        }
        __syncthreads();

        // state phase (batch = w)
        const float* rr = sRec + w * RECP;
        float zp0 = gz0 + rr[la],       zp1 = gz1 + rr[64 + la];
        float ip0 = gi0 + rr[128 + la], ip1 = gi1 + rr[192 + la];
        float fp0 = gf0 + rr[256 + la], fp1 = gf1 + rr[320 + la];
        float op0 = go0 + rr[384 + la], op1 = go1 + rr[448 + la];

        float e20 = __expf(2.f * zp0), e21 = __expf(2.f * zp1);
        float z0 = (e20 - 1.f) / (e20 + 1.f), z1 = (e21 - 1.f) / (e21 + 1.f);
        float o0 = 1.f / (1.f + __expf(-op0)), o1 = 1.f / (1.f + __expf(-op1));
        float mn0 = fmaxf(fp0 + m0, ip0), mn1 = fmaxf(fp1 + m1, ip1);
        float ie0 = __expf(ip0 - mn0), ie1 = __expf(ip1 - mn1);
        float fe0 = __expf(fp0 + m0 - mn0), fe1 = __expf(fp1 + m1 - mn1);
        c0 = fe0 * c0 + ie0 * z0;  c1 = fe1 * c1 + ie1 * z1;
        n0s = fe0 * n0s + ie0;     n1s = fe1 * n1s + ie1;
        m0 = mn0;                  m1 = mn1;
        float h0 = o0 * (c0 / n0s), h1 = o1 * (c1 / n1s);

        // GroupNorm over 128 dims of batch w — pure in-wave shuffle
        float s = h0 + h1, ss = h0 * h0 + h1 * h1;
#pragma unroll
        for (int off = 32; off >= 1; off >>= 1) {
            s += __shfl_xor(s, off);
            ss += __shfl_xor(ss, off);
        }
        float mu = s * (1.f / 128.f);
        float var = ss * (1.f / 128.f) - mu * mu;
        float rs = rsqrtf(var + 1e-5f);
        size_t base = ((size_t)(b0 + w) * 12 + step) * 1024 + head * 128;
        hnb[base + la] = f2b((h0 - mu) * rs * gg0 + gb0);
        hnb[base + la + 64] = f2b((h1 - mu) * rs * gg1 + gb1);

        // publish h (bf16) for next step's A fragments
        sHb[w * HBP + la] = f2b(h0);
        sHb[w * HBP + la + 64] = f2b(h1);
        __syncthreads();
    }
}

// ------------------------------ gate kernel --------------------------------

__global__ __launch_bounds__(256) void gate_kernel(
    const unsigned short* __restrict__ lr, unsigned short* __restrict__ glr)
{
    size_t gid = (size_t)blockIdx.x * 256 + threadIdx.x;  // 6144*1024
    size_t m = gid >> 10;
    int j = (int)(gid & 1023);
    float lf = b2f(lr[m * 2048 + j]);
    float rt = b2f(lr[m * 2048 + 1024 + j]);
    glr[gid] = f2b(gelu_exact(lf) * rt);
}

// ------------------ tail A: conv1(12->48)+gelu+LN(length) ------------------
// grid (512 batches, 6 chunks of 8 out-channels), block 256.

__global__ __launch_bounds__(256) void tail_conv1_ln_kernel(
    const float* __restrict__ y, const float* __restrict__ w1,
    const float* __restrict__ b1, const float* __restrict__ lng,
    const float* __restrict__ lnb, unsigned short* __restrict__ z)
{
    __shared__ float sX[12 * 1024];          // 48 KB
    __shared__ unsigned short sZ[8][1024];   // 16 KB
    __shared__ float sred[2][8][4];
    const int b = blockIdx.x;
    const int o0 = blockIdx.y * 8;
    const int t = threadIdx.x;

    const float4_t* srcv = (const float4_t*)(y + (size_t)b * 12288);
    float4_t* dstv = (float4_t*)sX;
    for (int i = t; i < 3072; i += 256) dstv[i] = srcv[i];
    __syncthreads();

    float s[8], ss[8];
#pragma unroll
    for (int o = 0; o < 8; o++) { s[o] = 0.f; ss[o] = 0.f; }

    for (int p = 0; p < 4; p++) {
        const int l = t + p * 256;
        float vm[12], v0[12], vp[12];
#pragma unroll
        for (int ci = 0; ci < 12; ci++) {
            v0[ci] = sX[ci * 1024 + l];
            vm[ci] = (l > 0) ? sX[ci * 1024 + l - 1] : 0.f;
            vp[ci] = (l < 1023) ? sX[ci * 1024 + l + 1] : 0.f;
        }
#pragma unroll
        for (int o = 0; o < 8; o++) {
            const float* wp = w1 + (o0 + o) * 36;   // uniform -> SGPR
            float a = b1[o0 + o];
#pragma unroll
            for (int ci = 0; ci < 12; ci++)
                a += vm[ci] * wp[ci * 3] + v0[ci] * wp[ci * 3 + 1] + vp[ci] * wp[ci * 3 + 2];
            float g = gelu_exact(a);
            s[o] += g; ss[o] += g * g;
            sZ[o][l] = f2b(g);
        }
    }
    const int wv = t >> 6, la = t & 63;
#pragma unroll
    for (int o = 0; o < 8; o++) {
        float a = s[o], q = ss[o];
#pragma unroll
        for (int off = 32; off >= 1; off >>= 1) {
            a += __shfl_xor(a, off);
            q += __shfl_xor(q, off);
        }
        if (la == 0) { sred[0][o][wv] = a; sred[1][o][wv] = q; }
    }
    __syncthreads();
    float mu[8], rs[8];
#pragma unroll
    for (int o = 0; o < 8; o++) {
        float S = sred[0][o][0] + sred[0][o][1] + sred[0][o][2] + sred[0][o][3];
        float Q = sred[1][o][0] + sred[1][o][1] + sred[1][o][2] + sred[1][o][3];
        float m = S * (1.f / 1024.f);
        float var = Q * (1.f / 1024.f) - m * m;
        mu[o] = m;
        rs[o] = rsqrtf(var + 1e-5f);
    }
    for (int p = 0; p < 4; p++) {
        const int l = t + p * 256;
        const float lg = lng[l], lb = lnb[l];
#pragma unroll
        for (int o = 0; o < 8; o++) {
            float v = b2f(sZ[o][l]);
            z[((size_t)b * 48 + o0 + o) * 1024 + l] = f2b((v - mu[o]) * rs[o] * lg + lb);
        }
    }
}

// -------------------- tail B: conv2(48->12) + skip -------------------------
// grid (512 batches, 4 tiles of 256 positions), block 256.

__global__ __launch_bounds__(256) void tail_conv2_kernel(
    const unsigned short* __restrict__ z, const float* __restrict__ skip,
    const float* __restrict__ w2, const float* __restrict__ b2,
    float* __restrict__ out)
{
    __shared__ unsigned short sZt[48][258];
    const int b = blockIdx.x;
    const int l0 = blockIdx.y * 256;
    const int t = threadIdx.x;
    const unsigned short* zb = z + (size_t)b * 49152;
    for (int ci = 0; ci < 48; ci++) {
        int l = l0 - 1 + t;
        sZt[ci][t] = (l >= 0 && l < 1024) ? zb[ci * 1024 + l] : (unsigned short)0;
        if (t < 2) {
            int l2 = l0 - 1 + 256 + t;
            sZt[ci][256 + t] = (l2 >= 0 && l2 < 1024) ? zb[ci * 1024 + l2] : (unsigned short)0;
        }
    }
    __syncthreads();
    float acc[12];
#pragma unroll
    for (int o = 0; o < 12; o++) acc[o] = b2[o];
    for (int ci = 0; ci < 48; ci++) {
        float zm = b2f(sZt[ci][t]);
        float z0 = b2f(sZt[ci][t + 1]);
        float zp = b2f(sZt[ci][t + 2]);
        const float* wp = w2 + ci * 3;   // uniform -> SGPR
#pragma unroll
        for (int o = 0; o < 12; o++)
            acc[o] += zm * wp[o * 144] + z0 * wp[o * 144 + 1] + zp * wp[o * 144 + 2];
    }
    const int l = l0 + t;
#pragma unroll
    for (int o = 0; o < 12; o++) {
        size_t idx = (size_t)b * 12288 + o * 1024 + l;
        out[idx] = acc[o] + skip[idx];
    }
}

// ------------------------------ launcher -----------------------------------

extern "C" void kernel_launch(void* const* d_in, const int* in_sizes, int n_in,
                              void* d_out, int out_size, void* d_ws, size_t ws_size,
                              hipStream_t stream)
{
    (void)in_sizes; (void)n_in; (void)out_size; (void)ws_size;
    const float* x      = (const float*)d_in[0];
    const float* ln_g   = (const float*)d_in[1];
    const float* ln_b   = (const float*)d_in[2];
    const float* fc1_w  = (const float*)d_in[3];
    const float* fc1_b  = (const float*)d_in[4];
    const float* fc2_w  = (const float*)d_in[5];
    const float* fc2_b  = (const float*)d_in[6];
    const float* conv1_w= (const float*)d_in[7];
    const float* conv1_b= (const float*)d_in[8];
    const float* conv2_w= (const float*)d_in[9];
    const float* conv2_b= (const float*)d_in[10];
    const float* xl_g   = (const float*)d_in[11];
    const float* xl_b   = (const float*)d_in[12];
    const float* Wg     = (const float*)d_in[13];
    const float* bg     = (const float*)d_in[14];
    const float* Rg     = (const float*)d_in[15];
    const float* gn_g   = (const float*)d_in[16];
    const float* gn_b   = (const float*)d_in[17];
    const float* upl_w  = (const float*)d_in[18];
    const float* upl_b  = (const float*)d_in[19];
    const float* upr_w  = (const float*)d_in[20];
    const float* upr_b  = (const float*)d_in[21];
    const float* down_w = (const float*)d_in[22];
    const float* down_b = (const float*)d_in[23];

    char* ws = (char*)d_ws;
    size_t off = 0;
    auto alloc = [&](size_t bytes) -> char* {
        char* p = ws + off;
        off = (off + bytes + 255) & ~(size_t)255;
        return p;
    };
    float* xn            = (float*)alloc(25165824);          // 6144x1024 f32
    float* xc            = (float*)alloc(25165824);
    float* x1            = (float*)alloc(25165824);
    unsigned short* xn2b = (unsigned short*)alloc(12582912); // 6144x1024 bf16
    unsigned short* gxb  = (unsigned short*)alloc(50331648); // 6144x4096 bf16
    unsigned short* hnb  = (unsigned short*)alloc(12582912);
    unsigned short* lrb  = (unsigned short*)alloc(25165824); // 6144x2048 bf16
    unsigned short* glrb = (unsigned short*)alloc(12582912);
    float* yb            = (float*)alloc(25165824);
    unsigned short* WgT  = (unsigned short*)alloc(8388608);  // 4096x1024 bf16
    unsigned short* WupT = (unsigned short*)alloc(4194304);  // 2048x1024 bf16
    unsigned short* WdT  = (unsigned short*)alloc(2097152);  // 1024x1024 bf16
    float* bup           = (float*)alloc(8192);              // 2048 f32
    // z (tail intermediate, 512x48x1024 bf16 = 50.3 MB) reuses gxb, which is
    // dead after slstm_rec_kernel.
    unsigned short* zb   = gxb;

    // weight prep
    transpose_bf16_k<<<dim3(128, 32), 256, 0, stream>>>(Wg, WgT, 1024, 4096);
    transpose_bf16_k<<<dim3(32, 32), 256, 0, stream>>>(upl_w, WupT, 1024, 1024);
    transpose_bf16_k<<<dim3(32, 32), 256, 0, stream>>>(upr_w, WupT + 1024 * 1024, 1024, 1024);
    transpose_bf16_k<<<dim3(32, 32), 256, 0, stream>>>(down_w, WdT, 1024, 1024);
    cat_bias_k<<<8, 256, 0, stream>>>(upl_b, upr_b, bup);

    // main pipeline
    ln_kernel<0><<<6144, 256, 0, stream>>>(x, ln_g, ln_b, xn);
    fc_kernel<<<2048, 256, 0, stream>>>(xn, fc1_w, fc1_b, fc2_w, fc2_b, xc, x1);
    ln_kernel<1><<<6144, 256, 0, stream>>>(x1, xl_g, xl_b, xn2b);
    gemm_kernel<0><<<dim3(32, 48), 256, 0, stream>>>(
        xn2b, WgT, bg, gxb, 6144, 4096, 1024, nullptr, nullptr, nullptr);
    slstm_rec_kernel<<<dim3(8, 32), 1024, 0, stream>>>(Rg, gxb, gn_g, gn_b, hnb);
    gemm_kernel<0><<<dim3(16, 48), 256, 0, stream>>>(
        hnb, WupT, bup, lrb, 6144, 2048, 1024, nullptr, nullptr, nullptr);
    gate_kernel<<<24576, 256, 0, stream>>>(lrb, glrb);
    gemm_kernel<2><<<dim3(8, 48), 256, 0, stream>>>(
        glrb, WdT, down_b, yb, 6144, 1024, 1024, xc, x1, xn);
    tail_conv1_ln_kernel<<<dim3(512, 6), 256, 0, stream>>>(
        yb, conv1_w, conv1_b, ln_g, ln_b, zb);
    tail_conv2_kernel<<<dim3(512, 4), 256, 0, stream>>>(
        zb, xn, conv2_w, conv2_b, (float*)d_out);
}

// Round 5
// 482.422 us; speedup vs baseline: 3.9916x; 1.1788x over previous
//
#include <hip/hip_runtime.h>
#include <math.h>

// ---------------------------------------------------------------------------
// xLSTM decoder block, MI355X gfx950.
// Pipeline (all flat (b*12+ch)*1024+l layout):
//  prep:  weights -> bf16 (Wg/upl/upr/down transposed to [n][k])
//  ln1:   x -> xn (fp32)                           [skip]
//  fc:    xn -> xc (fp32), x1 (fp32)               (conv12->12 k3 + 1x1)
//  ln2:   x1 -> xn2 (bf16)
//  gemm0: xn2 @ WgT + bg -> gx (bf16, 6144x4096)
//  rec:   MFMA sLSTM per (head, 16 batches): R^T in VGPR B-fragments,
//         h->rec via mfma 16x16x32, state+GroupNorm in-wave -> hn (bf16)
//  gemm0: hn @ WupT + [upl_b|upr_b] -> lr (bf16, 6144x2048)
//  gate:  glr = gelu(left)*right (bf16)
//  gemm2: glr @ WdT + down_b ; epilogue y = silu(xc)*(acc+down_b+x1) + xn
//  tail:  FUSED conv1(12->48)+gelu+LN(len)+conv2(48->12)+skip, one block per
//         batch, z fully LDS-resident (Round-5: was two kernels with a 100 MB
//         z round-trip and 6x redundant y staging at 2 waves/SIMD).
// ---------------------------------------------------------------------------

typedef short short8_t __attribute__((ext_vector_type(8)));
typedef float floatx4 __attribute__((ext_vector_type(4)));
typedef float float4_t __attribute__((ext_vector_type(4)));

typedef unsigned int u32;
typedef const __attribute__((address_space(1))) u32 gu32;
typedef __attribute__((address_space(3))) u32 lu32;

static __device__ __forceinline__ float b2f(unsigned short u) {
    unsigned v = ((unsigned)u) << 16;
    return __builtin_bit_cast(float, v);
}
static __device__ __forceinline__ unsigned short f2b(float f) {
    unsigned u = __builtin_bit_cast(unsigned, f);
    u += 0x7FFFu + ((u >> 16) & 1u);   // RNE
    return (unsigned short)(u >> 16);
}
static __device__ __forceinline__ float gelu_exact(float x) {
    return 0.5f * x * (1.f + erff(x * 0.70710678118654752f));
}

// --------------------------- weight prep ----------------------------------

__global__ __launch_bounds__(256) void transpose_bf16_k(
    const float* __restrict__ src, unsigned short* __restrict__ dst, int K, int N)
{   // dst[n*K+k] = bf16(src[k*N+n]); grid (N/32, K/32), block 256
    __shared__ unsigned short tl[32][33];
    const int n0 = blockIdx.x * 32, k0 = blockIdx.y * 32;
    const int tx = threadIdx.x & 31, ty = threadIdx.x >> 5; // ty 0..7
#pragma unroll
    for (int r = 0; r < 4; r++) {
        int k = ty + r * 8;
        tl[tx][k] = f2b(src[(size_t)(k0 + k) * N + n0 + tx]);
    }
    __syncthreads();
#pragma unroll
    for (int r = 0; r < 4; r++) {
        int n = ty * 4 + r;
        dst[(size_t)(n0 + n) * K + k0 + tx] = tl[n][tx];
    }
}

__global__ __launch_bounds__(256) void cat_bias_k(
    const float* __restrict__ a, const float* __restrict__ b, float* __restrict__ o)
{
    int gid = blockIdx.x * 256 + threadIdx.x;   // 2048 total
    o[gid] = (gid < 1024) ? a[gid] : b[gid - 1024];
}

// ------------------------------ layernorm ----------------------------------

template <int BF16OUT>
__global__ __launch_bounds__(256) void ln_kernel(
    const float* __restrict__ in, const float* __restrict__ g,
    const float* __restrict__ be, void* __restrict__ outp)
{
    const int row = blockIdx.x;
    const float* xr = in + (size_t)row * 1024;
    const int t = threadIdx.x;
    float v[4];
    float s = 0.f, ss = 0.f;
#pragma unroll
    for (int u = 0; u < 4; u++) {
        float q = xr[t + u * 256];
        v[u] = q; s += q; ss += q * q;
    }
#pragma unroll
    for (int off = 32; off >= 1; off >>= 1) {
        s += __shfl_xor(s, off);
        ss += __shfl_xor(ss, off);
    }
    __shared__ float red[8];
    const int wv = t >> 6, la = t & 63;
    if (la == 0) { red[wv] = s; red[4 + wv] = ss; }
    __syncthreads();
    s = red[0] + red[1] + red[2] + red[3];
    ss = red[4] + red[5] + red[6] + red[7];
    float mu = s * (1.f / 1024.f);
    float var = ss * (1.f / 1024.f) - mu * mu;
    float rs = rsqrtf(var + 1e-5f);
#pragma unroll
    for (int u = 0; u < 4; u++) {
        int i = t + u * 256;
        float yv = (v[u] - mu) * rs * g[i] + be[i];
        if (BF16OUT)
            ((unsigned short*)outp)[(size_t)row * 1024 + i] = f2b(yv);
        else
            ((float*)outp)[(size_t)row * 1024 + i] = yv;
    }
}

// ---------------------- fc1 (conv k3) + fc2 (1x1) --------------------------

__global__ __launch_bounds__(256) void fc_kernel(
    const float* __restrict__ xn,
    const float* __restrict__ w1, const float* __restrict__ b1,
    const float* __restrict__ w2, const float* __restrict__ b2,
    float* __restrict__ xc, float* __restrict__ x1)
{
    const int t = threadIdx.x;
    const int gid = blockIdx.x * 256 + t;
    const int b = gid >> 10, l = gid & 1023;
    const float* xb = xn + (size_t)b * 12288;
    float inm[12], in0[12], inp[12];
#pragma unroll
    for (int ci = 0; ci < 12; ci++) {
        in0[ci] = xb[ci * 1024 + l];
        inm[ci] = (l > 0) ? xb[ci * 1024 + l - 1] : 0.f;
        inp[ci] = (l < 1023) ? xb[ci * 1024 + l + 1] : 0.f;
    }
    float xcv[12];
#pragma unroll
    for (int o = 0; o < 12; o++) {
        float a = b1[o];
#pragma unroll
        for (int ci = 0; ci < 12; ci++) {
            const float* wp = w1 + o * 36 + ci * 3;  // uniform -> s_load
            a += inm[ci] * wp[0] + in0[ci] * wp[1] + inp[ci] * wp[2];
        }
        xcv[o] = a;
        xc[(size_t)b * 12288 + o * 1024 + l] = a;
    }
#pragma unroll
    for (int o = 0; o < 12; o++) {
        float a = b2[o];
#pragma unroll
        for (int ci = 0; ci < 12; ci++) a += xcv[ci] * w2[o * 12 + ci];
        x1[(size_t)b * 12288 + o * 1024 + l] = a;
    }
}

// ------------------------------ bf16 GEMM ----------------------------------
// C[m][n] = sum_k A[m][k]*BT[n][k] + bias[n]; 128x128 tile, 4 waves 2x2,
// each wave 64x64 via 4x4 of mfma_f32_16x16x32_bf16. Staging via
// global_load_lds width-16: thread t's dest byte = 16*t.
// MODE 0: store bf16.  MODE 2: y = silu(xc)*(acc+bias+x1) + skip, store fp32.

template <int MODE>
__global__ __launch_bounds__(256) void gemm_kernel(
    const unsigned short* __restrict__ A, const unsigned short* __restrict__ BT,
    const float* __restrict__ bias, void* __restrict__ out,
    int M, int N, int K,
    const float* __restrict__ xc, const float* __restrict__ x1,
    const float* __restrict__ skip)
{
    __shared__ __align__(16) unsigned short sA[128 * 32];
    __shared__ __align__(16) unsigned short sB[128 * 32];
    const int t = threadIdx.x;
    const int m0 = blockIdx.y * 128;
    const int n0 = blockIdx.x * 128;
    const int w = t >> 6;
    const int lane = t & 63;
    const int wr = (w >> 1) * 64;
    const int wc = (w & 1) * 64;
    const int lrow = lane & 15;
    const int quad = lane >> 4;
    const int row_l = t >> 2;          // 0..63
    const int cs = (t & 3) * 8;        // 0,8,16,24

    const unsigned short* gA0 = A + (size_t)(m0 + row_l) * K + cs;
    const unsigned short* gA1 = A + (size_t)(m0 + row_l + 64) * K + cs;
    const unsigned short* gB0 = BT + (size_t)(n0 + row_l) * K + cs;
    const unsigned short* gB1 = BT + (size_t)(n0 + row_l + 64) * K + cs;
    unsigned short* lA0 = sA + w * 512;          // wave-uniform LDS bases
    unsigned short* lA1 = sA + 2048 + w * 512;
    unsigned short* lB0 = sB + w * 512;
    unsigned short* lB1 = sB + 2048 + w * 512;

    floatx4 acc[4][4];
#pragma unroll
    for (int i = 0; i < 4; i++)
#pragma unroll
        for (int j = 0; j < 4; j++) acc[i][j] = (floatx4)0.f;

    for (int k0 = 0; k0 < K; k0 += 32) {
        __syncthreads();
        __builtin_amdgcn_global_load_lds((gu32*)(gA0 + k0), (lu32*)lA0, 16, 0, 0);
        __builtin_amdgcn_global_load_lds((gu32*)(gA1 + k0), (lu32*)lA1, 16, 0, 0);
        __builtin_amdgcn_global_load_lds((gu32*)(gB0 + k0), (lu32*)lB0, 16, 0, 0);
        __builtin_amdgcn_global_load_lds((gu32*)(gB1 + k0), (lu32*)lB1, 16, 0, 0);
        __syncthreads();
        short8_t af[4], bfr[4];
#pragma unroll
        for (int i = 0; i < 4; i++) {
            af[i] = *(const short8_t*)(sA + (wr + i * 16 + lrow) * 32 + quad * 8);
            bfr[i] = *(const short8_t*)(sB + (wc + i * 16 + lrow) * 32 + quad * 8);
        }
#pragma unroll
        for (int i = 0; i < 4; i++)
#pragma unroll
            for (int j = 0; j < 4; j++)
                acc[i][j] = __builtin_amdgcn_mfma_f32_16x16x32_bf16(
                    af[i], bfr[j], acc[i][j], 0, 0, 0);
    }

#pragma unroll
    for (int i = 0; i < 4; i++) {
#pragma unroll
        for (int j = 0; j < 4; j++) {
#pragma unroll
            for (int r = 0; r < 4; r++) {
                const int gm = m0 + wr + i * 16 + quad * 4 + r;
                const int gn = n0 + wc + j * 16 + lrow;
                const size_t idx = (size_t)gm * N + gn;
                float v = acc[i][j][r] + bias[gn];
                if (MODE == 0) {
                    ((unsigned short*)out)[idx] = f2b(v);
                } else {
                    float xcv = xc[idx];
                    float sig = xcv / (1.f + __expf(-xcv));
                    ((float*)out)[idx] = sig * (v + x1[idx]) + skip[idx];
                }
            }
        }
    }
}

// ------------------- sLSTM recurrence + GroupNorm (MFMA) -------------------
// grid (NH=8, B/16=32) = 256 blocks (1/CU), block 1024 (16 waves, 4/SIMD).
// Per step: rec(16x512) = h(16x128) @ Rg[head]^T(128x512) via 16x16x32 MFMA.
// Wave w owns gate cols [32w,32w+32): B-fragments (32 VGPR) held for all steps.
// State phase: wave = local batch, lane la owns hs=la and hs=la+64; GroupNorm
// is an in-wave shuffle reduction. h round-trips through LDS as bf16 (A frags).

#define RECP 516   // f32 row stride for sRec (2-way bank aliasing only)
#define HBP  136   // bf16 row stride for sHb

__global__ __launch_bounds__(1024, 4) void slstm_rec_kernel(
    const float* __restrict__ Rg,             // [8][512][128] f32
    const unsigned short* __restrict__ gxb,   // [B][12][4096] bf16
    const float* __restrict__ gn_g, const float* __restrict__ gn_b,
    unsigned short* __restrict__ hnb)         // [B][12][1024] bf16
{
    __shared__ __align__(16) float sRec[16 * RECP];           // 33.0 KB
    __shared__ __align__(16) unsigned short sHb[16 * HBP];    // 4.4 KB
    const int head = blockIdx.x;
    const int b0 = blockIdx.y * 16;
    const int t = threadIdx.x;
    const int w = t >> 6;          // wave id = MFMA col-slice = state batch
    const int lane = t & 63;
    const int quad = lane >> 4;
    const int l16 = lane & 15;

    // ---- B fragments: Bf[jt][kk] holds Rg[head][32w+16jt+l16][32kk+8quad+j]
    short8_t Bf[2][4];
    {
        const float* Rh = Rg + (size_t)head * 65536;
#pragma unroll
        for (int jt = 0; jt < 2; jt++)
#pragma unroll
            for (int kk = 0; kk < 4; kk++) {
                const float* src =
                    Rh + (size_t)(w * 32 + jt * 16 + l16) * 128 + kk * 32 + quad * 8;
                short8_t v;
#pragma unroll
                for (int j = 0; j < 8; j++) v[j] = (short)f2b(src[j]);
                Bf[jt][kk] = v;
            }
    }

    for (int i = t; i < 16 * HBP; i += 1024) sHb[i] = 0;

    // state-role constants (wave = local batch, lane la -> hs = la, la+64)
    const int la = lane;
    float c0 = 0.f, n0s = 0.f, m0 = 0.f;
    float c1 = 0.f, n1s = 0.f, m1 = 0.f;
    const float gg0 = gn_g[head * 128 + la];
    const float gg1 = gn_g[head * 128 + la + 64];
    const float gb0 = gn_b[head * 128 + la];
    const float gb1 = gn_b[head * 128 + la + 64];

    __syncthreads();

    for (int step = 0; step < 12; step++) {
        // gx pre-activation loads (global; overlap with MFMA phase)
        const unsigned short* gp =
            gxb + ((size_t)(b0 + w) * 12 + step) * 4096 + head * 512;
        float gz0 = b2f(gp[la]),       gz1 = b2f(gp[64 + la]);
        float gi0 = b2f(gp[128 + la]), gi1 = b2f(gp[192 + la]);
        float gf0 = b2f(gp[256 + la]), gf1 = b2f(gp[320 + la]);
        float go0 = b2f(gp[384 + la]), go1 = b2f(gp[448 + la]);

        // MFMA phase: rec = h @ R^T for this wave's 32 cols
        short8_t Af[4];
#pragma unroll
        for (int kk = 0; kk < 4; kk++)
            Af[kk] = *(const short8_t*)(sHb + l16 * HBP + kk * 32 + quad * 8);
        floatx4 D0 = (floatx4)0.f, D1 = (floatx4)0.f;
#pragma unroll
        for (int kk = 0; kk < 4; kk++) {
            D0 = __builtin_amdgcn_mfma_f32_16x16x32_bf16(Af[kk], Bf[0][kk], D0, 0, 0, 0);
            D1 = __builtin_amdgcn_mfma_f32_16x16x32_bf16(Af[kk], Bf[1][kk], D1, 0, 0, 0);
        }
#pragma unroll
        for (int r = 0; r < 4; r++) {
            sRec[(quad * 4 + r) * RECP + w * 32 + l16] = D0[r];
            sRec[(quad * 4 + r) * RECP + w * 32 + 16 + l16] = D1[r];
        }
        __syncthreads();

        // state phase (batch = w)
        const float* rr = sRec + w * RECP;
        float zp0 = gz0 + rr[la],       zp1 = gz1 + rr[64 + la];
        float ip0 = gi0 + rr[128 + la], ip1 = gi1 + rr[192 + la];
        float fp0 = gf0 + rr[256 + la], fp1 = gf1 + rr[320 + la];
        float op0 = go0 + rr[384 + la], op1 = go1 + rr[448 + la];

        float e20 = __expf(2.f * zp0), e21 = __expf(2.f * zp1);
        float z0 = (e20 - 1.f) / (e20 + 1.f), z1 = (e21 - 1.f) / (e21 + 1.f);
        float o0 = 1.f / (1.f + __expf(-op0)), o1 = 1.f / (1.f + __expf(-op1));
        float mn0 = fmaxf(fp0 + m0, ip0), mn1 = fmaxf(fp1 + m1, ip1);
        float ie0 = __expf(ip0 - mn0), ie1 = __expf(ip1 - mn1);
        float fe0 = __expf(fp0 + m0 - mn0), fe1 = __expf(fp1 + m1 - mn1);
        c0 = fe0 * c0 + ie0 * z0;  c1 = fe1 * c1 + ie1 * z1;
        n0s = fe0 * n0s + ie0;     n1s = fe1 * n1s + ie1;
        m0 = mn0;                  m1 = mn1;
        float h0 = o0 * (c0 / n0s), h1 = o1 * (c1 / n1s);

        // GroupNorm over 128 dims of batch w — pure in-wave shuffle
        float s = h0 + h1, ss = h0 * h0 + h1 * h1;
#pragma unroll
        for (int off = 32; off >= 1; off >>= 1) {
            s += __shfl_xor(s, off);
            ss += __shfl_xor(ss, off);
        }
        float mu = s * (1.f / 128.f);
        float var = ss * (1.f / 128.f) - mu * mu;
        float rs = rsqrtf(var + 1e-5f);
        size_t base = ((size_t)(b0 + w) * 12 + step) * 1024 + head * 128;
        hnb[base + la] = f2b((h0 - mu) * rs * gg0 + gb0);
        hnb[base + la + 64] = f2b((h1 - mu) * rs * gg1 + gb1);

        // publish h (bf16) for next step's A fragments
        sHb[w * HBP + la] = f2b(h0);
        sHb[w * HBP + la + 64] = f2b(h1);
        __syncthreads();
    }
}

// ------------------------------ gate kernel --------------------------------

__global__ __launch_bounds__(256) void gate_kernel(
    const unsigned short* __restrict__ lr, unsigned short* __restrict__ glr)
{
    size_t gid = (size_t)blockIdx.x * 256 + threadIdx.x;  // 6144*1024
    size_t m = gid >> 10;
    int j = (int)(gid & 1023);
    float lf = b2f(lr[m * 2048 + j]);
    float rt = b2f(lr[m * 2048 + 1024 + j]);
    glr[gid] = f2b(gelu_exact(lf) * rt);
}

// ---------------- fused tail: conv1+gelu+LN(len)+conv2+skip ----------------
// grid 512 (one block per batch), block 1024 (16 waves, 4/SIMD), 1 block/CU.
// y staged bf16 (24 KB), z LDS-resident (99 KB) — no z global round-trip.
// Thread t = position l. Weights via wave-uniform s_load (spill-free).

__global__ __launch_bounds__(1024, 4) void tail_fused_kernel(
    const float* __restrict__ y, const float* __restrict__ skip,
    const float* __restrict__ w1, const float* __restrict__ b1,
    const float* __restrict__ w2, const float* __restrict__ b2,
    const float* __restrict__ lng, const float* __restrict__ lnb,
    float* __restrict__ out)
{
    __shared__ unsigned short sY[12][1032];   // 24.2 KB
    __shared__ unsigned short sZ[48][1032];   // 96.8 KB
    __shared__ float sLg[1024], sLb[1024];    // 8 KB
    __shared__ float sMR[48][2];
    const int b = blockIdx.x;
    const int t = threadIdx.x;                // position 0..1023

    {
        const float* yb = y + (size_t)b * 12288;
#pragma unroll
        for (int r = 0; r < 12; r++) sY[r][t] = f2b(yb[r * 1024 + t]);
    }
    sLg[t] = lng[t];
    sLb[t] = lnb[t];
    __syncthreads();

    // conv1 (12->48, k3) + gelu -> sZ
    float vm[12], v0[12], vp[12];
#pragma unroll
    for (int ci = 0; ci < 12; ci++) {
        v0[ci] = b2f(sY[ci][t]);
        vm[ci] = (t > 0) ? b2f(sY[ci][t - 1]) : 0.f;
        vp[ci] = (t < 1023) ? b2f(sY[ci][t + 1]) : 0.f;
    }
    for (int o = 0; o < 48; o++) {
        const float* wp = w1 + o * 36;        // uniform -> SGPR
        float a = b1[o];
#pragma unroll
        for (int ci = 0; ci < 12; ci++)
            a += vm[ci] * wp[ci * 3] + v0[ci] * wp[ci * 3 + 1] + vp[ci] * wp[ci * 3 + 2];
        sZ[o][t] = f2b(gelu_exact(a));
    }
    __syncthreads();

    // LN stats over length: wave w handles channels 3w..3w+2
    {
        const int w = t >> 6, la = t & 63;
        for (int o = w * 3; o < w * 3 + 3; o++) {
            float s = 0.f, ss = 0.f;
#pragma unroll
            for (int u = 0; u < 16; u++) {
                float v = b2f(sZ[o][la + u * 64]);
                s += v; ss += v * v;
            }
#pragma unroll
            for (int off = 32; off >= 1; off >>= 1) {
                s += __shfl_xor(s, off);
                ss += __shfl_xor(ss, off);
            }
            if (la == 0) {
                float mu = s * (1.f / 1024.f);
                float var = ss * (1.f / 1024.f) - mu * mu;
                sMR[o][0] = mu;
                sMR[o][1] = rsqrtf(var + 1e-5f);
            }
        }
    }
    __syncthreads();

    // conv2 (48->12, k3) with normalize-on-read + skip
    float acc[12];
#pragma unroll
    for (int o = 0; o < 12; o++) acc[o] = b2[o];
    const float lg0 = sLg[t], lb0 = sLb[t];
    const float lgm = (t > 0) ? sLg[t - 1] : 0.f;
    const float lbm = (t > 0) ? sLb[t - 1] : 0.f;
    const float lgp = (t < 1023) ? sLg[t + 1] : 0.f;
    const float lbp = (t < 1023) ? sLb[t + 1] : 0.f;
    for (int ci = 0; ci < 48; ci++) {
        const float mu = sMR[ci][0], rs = sMR[ci][1];
        float znm = (t > 0) ? ((b2f(sZ[ci][t - 1]) - mu) * rs * lgm + lbm) : 0.f;
        float zn0 = (b2f(sZ[ci][t]) - mu) * rs * lg0 + lb0;
        float znp = (t < 1023) ? ((b2f(sZ[ci][t + 1]) - mu) * rs * lgp + lbp) : 0.f;
        const float* wp = w2 + ci * 3;        // uniform -> SGPR
#pragma unroll
        for (int o = 0; o < 12; o++)
            acc[o] += znm * wp[o * 144] + zn0 * wp[o * 144 + 1] + znp * wp[o * 144 + 2];
    }
    const size_t base = (size_t)b * 12288 + t;
#pragma unroll
    for (int o = 0; o < 12; o++) {
        size_t idx = base + (size_t)o * 1024;
        out[idx] = acc[o] + skip[idx];
    }
}

// ------------------------------ launcher -----------------------------------

extern "C" void kernel_launch(void* const* d_in, const int* in_sizes, int n_in,
                              void* d_out, int out_size, void* d_ws, size_t ws_size,
                              hipStream_t stream)
{
    (void)in_sizes; (void)n_in; (void)out_size; (void)ws_size;
    const float* x      = (const float*)d_in[0];
    const float* ln_g   = (const float*)d_in[1];
    const float* ln_b   = (const float*)d_in[2];
    const float* fc1_w  = (const float*)d_in[3];
    const float* fc1_b  = (const float*)d_in[4];
    const float* fc2_w  = (const float*)d_in[5];
    const float* fc2_b  = (const float*)d_in[6];
    const float* conv1_w= (const float*)d_in[7];
    const float* conv1_b= (const float*)d_in[8];
    const float* conv2_w= (const float*)d_in[9];
    const float* conv2_b= (const float*)d_in[10];
    const float* xl_g   = (const float*)d_in[11];
    const float* xl_b   = (const float*)d_in[12];
    const float* Wg     = (const float*)d_in[13];
    const float* bg     = (const float*)d_in[14];
    const float* Rg     = (const float*)d_in[15];
    const float* gn_g   = (const float*)d_in[16];
    const float* gn_b   = (const float*)d_in[17];
    const float* upl_w  = (const float*)d_in[18];
    const float* upl_b  = (const float*)d_in[19];
    const float* upr_w  = (const float*)d_in[20];
    const float* upr_b  = (const float*)d_in[21];
    const float* down_w = (const float*)d_in[22];
    const float* down_b = (const float*)d_in[23];

    char* ws = (char*)d_ws;
    size_t off = 0;
    auto alloc = [&](size_t bytes) -> char* {
        char* p = ws + off;
        off = (off + bytes + 255) & ~(size_t)255;
        return p;
    };
    float* xn            = (float*)alloc(25165824);          // 6144x1024 f32
    float* xc            = (float*)alloc(25165824);
    float* x1            = (float*)alloc(25165824);
    unsigned short* xn2b = (unsigned short*)alloc(12582912); // 6144x1024 bf16
    unsigned short* gxb  = (unsigned short*)alloc(50331648); // 6144x4096 bf16
    unsigned short* hnb  = (unsigned short*)alloc(12582912);
    unsigned short* lrb  = (unsigned short*)alloc(25165824); // 6144x2048 bf16
    unsigned short* glrb = (unsigned short*)alloc(12582912);
    float* yb            = (float*)alloc(25165824);
    unsigned short* WgT  = (unsigned short*)alloc(8388608);  // 4096x1024 bf16
    unsigned short* WupT = (unsigned short*)alloc(4194304);  // 2048x1024 bf16
    unsigned short* WdT  = (unsigned short*)alloc(2097152);  // 1024x1024 bf16
    float* bup           = (float*)alloc(8192);              // 2048 f32

    // weight prep
    transpose_bf16_k<<<dim3(128, 32), 256, 0, stream>>>(Wg, WgT, 1024, 4096);
    transpose_bf16_k<<<dim3(32, 32), 256, 0, stream>>>(upl_w, WupT, 1024, 1024);
    transpose_bf16_k<<<dim3(32, 32), 256, 0, stream>>>(upr_w, WupT + 1024 * 1024, 1024, 1024);
    transpose_bf16_k<<<dim3(32, 32), 256, 0, stream>>>(down_w, WdT, 1024, 1024);
    cat_bias_k<<<8, 256, 0, stream>>>(upl_b, upr_b, bup);

    // main pipeline
    ln_kernel<0><<<6144, 256, 0, stream>>>(x, ln_g, ln_b, xn);
    fc_kernel<<<2048, 256, 0, stream>>>(xn, fc1_w, fc1_b, fc2_w, fc2_b, xc, x1);
    ln_kernel<1><<<6144, 256, 0, stream>>>(x1, xl_g, xl_b, xn2b);
    gemm_kernel<0><<<dim3(32, 48), 256, 0, stream>>>(
        xn2b, WgT, bg, gxb, 6144, 4096, 1024, nullptr, nullptr, nullptr);
    slstm_rec_kernel<<<dim3(8, 32), 1024, 0, stream>>>(Rg, gxb, gn_g, gn_b, hnb);
    gemm_kernel<0><<<dim3(16, 48), 256, 0, stream>>>(
        hnb, WupT, bup, lrb, 6144, 2048, 1024, nullptr, nullptr, nullptr);
    gate_kernel<<<24576, 256, 0, stream>>>(lrb, glrb);
    gemm_kernel<2><<<dim3(8, 48), 256, 0, stream>>>(
        glrb, WdT, down_b, yb, 6144, 1024, 1024, xc, x1, xn);
    tail_fused_kernel<<<512, 1024, 0, stream>>>(
        yb, xn, conv1_w, conv1_b, conv2_w, conv2_b, ln_g, ln_b, (float*)d_out);
}

// Round 6
// 476.139 us; speedup vs baseline: 4.0443x; 1.0132x over previous
//
#include <hip/hip_runtime.h>
#include <math.h>

// ---------------------------------------------------------------------------
// xLSTM decoder block, MI355X gfx950.
// Pipeline (all flat (b*12+ch)*1024+l layout):
//  prep:  weights -> bf16 (Wg/upl/upr/down transposed to [n][k])
//  front: FUSED ln1 + fc1(conv k3) + fc2(1x1) + ln2 per batch
//         -> xn (f32 skip), xc (f32), x1 (f32), xn2 (bf16)
//  gemm0: xn2 @ WgT + bg -> gx (bf16, 6144x4096)
//  rec:   MFMA sLSTM per (head, 16 batches): R^T in VGPR B-fragments,
//         h->rec via mfma 16x16x32, state+GroupNorm in-wave -> hn (bf16)
//  gemm0: hn @ WupT + [upl_b|upr_b] -> lr (bf16, 6144x2048)
//  gate:  glr = gelu(left)*right (bf16)
//  gemm2: glr @ WdT + down_b ; epilogue y = silu(xc)*(acc+down_b+x1) + xn
//  tail:  FUSED conv1+gelu+LN(len)+conv2+skip. Round-6: 512-thread blocks,
//         thread = position pair (p, p+512) -> v_pk_fma_f32 packed math with
//         SGPR weight broadcast; channel-halves (24ch sZ) -> 74 KB LDS ->
//         2 blocks/CU (barrier overlap); tanh-gelu (erf was ~35 inst).
// ---------------------------------------------------------------------------

typedef short short8_t __attribute__((ext_vector_type(8)));
typedef float floatx4 __attribute__((ext_vector_type(4)));
typedef float float2_t __attribute__((ext_vector_type(2)));

typedef unsigned int u32;
typedef const __attribute__((address_space(1))) u32 gu32;
typedef __attribute__((address_space(3))) u32 lu32;

static __device__ __forceinline__ float b2f(unsigned short u) {
    unsigned v = ((unsigned)u) << 16;
    return __builtin_bit_cast(float, v);
}
static __device__ __forceinline__ unsigned short f2b(float f) {
    unsigned u = __builtin_bit_cast(unsigned, f);
    u += 0x7FFFu + ((u >> 16) & 1u);   // RNE
    return (unsigned short)(u >> 16);
}
static __device__ __forceinline__ float gelu_exact(float x) {
    return 0.5f * x * (1.f + erff(x * 0.70710678118654752f));
}
// tanh-form gelu (~10 inst vs ~35 for erf path); max abs err ~3e-3 — after
// LN + conv2 (0.02-scale weights) contribution to output < 1e-3.
static __device__ __forceinline__ float gelu_fast(float x) {
    float u = 0.7978845608f * x * (1.f + 0.044715f * x * x);
    u = fminf(fmaxf(u, -9.f), 9.f);          // avoid inf/inf NaN
    float e = __expf(2.f * u);
    float t = (e - 1.f) / (e + 1.f);
    return 0.5f * x * (1.f + t);
}

// --------------------------- weight prep ----------------------------------

__global__ __launch_bounds__(256) void transpose_bf16_k(
    const float* __restrict__ src, unsigned short* __restrict__ dst, int K, int N)
{   // dst[n*K+k] = bf16(src[k*N+n]); grid (N/32, K/32), block 256
    __shared__ unsigned short tl[32][33];
    const int n0 = blockIdx.x * 32, k0 = blockIdx.y * 32;
    const int tx = threadIdx.x & 31, ty = threadIdx.x >> 5; // ty 0..7
#pragma unroll
    for (int r = 0; r < 4; r++) {
        int k = ty + r * 8;
        tl[tx][k] = f2b(src[(size_t)(k0 + k) * N + n0 + tx]);
    }
    __syncthreads();
#pragma unroll
    for (int r = 0; r < 4; r++) {
        int n = ty * 4 + r;
        dst[(size_t)(n0 + n) * K + k0 + tx] = tl[n][tx];
    }
}

__global__ __launch_bounds__(256) void cat_bias_k(
    const float* __restrict__ a, const float* __restrict__ b, float* __restrict__ o)
{
    int gid = blockIdx.x * 256 + threadIdx.x;   // 2048 total
    o[gid] = (gid < 1024) ? a[gid] : b[gid - 1024];
}

// -------------- fused frontend: ln1 + fc1 + fc2 + ln2 ----------------------
// grid 512 (one block per batch), block 1024 (thread = position).
// LN over the length dim per (batch, channel); block-wide reduction.

__global__ __launch_bounds__(1024, 4) void frontend_fused_kernel(
    const float* __restrict__ x,
    const float* __restrict__ ln_g, const float* __restrict__ ln_b,
    const float* __restrict__ w1, const float* __restrict__ b1,
    const float* __restrict__ w2, const float* __restrict__ b2,
    const float* __restrict__ xl_g, const float* __restrict__ xl_b,
    float* __restrict__ xn, float* __restrict__ xc, float* __restrict__ x1,
    unsigned short* __restrict__ xn2b)
{
    __shared__ float sXn[12][1026];     // 49.2 KB
    __shared__ float sred[12][16][2];
    __shared__ float sMR[12][2];
    const int b = blockIdx.x;
    const int t = threadIdx.x;
    const int w = t >> 6, la = t & 63;
    const size_t boff = (size_t)b * 12288;

    float xv[12];
#pragma unroll
    for (int ci = 0; ci < 12; ci++) xv[ci] = x[boff + ci * 1024 + t];

    // LN1 stats (per channel, over 1024 positions)
#pragma unroll
    for (int ci = 0; ci < 12; ci++) {
        float s = xv[ci], ss = xv[ci] * xv[ci];
#pragma unroll
        for (int off = 32; off >= 1; off >>= 1) {
            s += __shfl_xor(s, off); ss += __shfl_xor(ss, off);
        }
        if (la == 0) { sred[ci][w][0] = s; sred[ci][w][1] = ss; }
    }
    __syncthreads();
    if (w < 12 && la == 0) {
        float s = 0.f, ss = 0.f;
        for (int u = 0; u < 16; u++) { s += sred[w][u][0]; ss += sred[w][u][1]; }
        float mu = s * (1.f / 1024.f);
        float var = ss * (1.f / 1024.f) - mu * mu;
        sMR[w][0] = mu; sMR[w][1] = rsqrtf(var + 1e-5f);
    }
    __syncthreads();
    {
        const float g0 = ln_g[t], be0 = ln_b[t];
#pragma unroll
        for (int ci = 0; ci < 12; ci++) {
            float v = (xv[ci] - sMR[ci][0]) * sMR[ci][1] * g0 + be0;
            sXn[ci][t] = v;
            xn[boff + ci * 1024 + t] = v;
            xv[ci] = v;   // reuse as center tap
        }
    }
    __syncthreads();

    // fc1 (conv 12->12 k3) + fc2 (1x1)
    float vmv[12], vpv[12];
#pragma unroll
    for (int ci = 0; ci < 12; ci++) {
        vmv[ci] = (t > 0) ? sXn[ci][t - 1] : 0.f;
        vpv[ci] = (t < 1023) ? sXn[ci][t + 1] : 0.f;
    }
    float xcv[12];
#pragma unroll
    for (int o = 0; o < 12; o++) {
        const float* wp = w1 + o * 36;          // uniform -> SGPR
        float a = b1[o];
#pragma unroll
        for (int ci = 0; ci < 12; ci++)
            a += vmv[ci] * wp[ci * 3] + xv[ci] * wp[ci * 3 + 1] + vpv[ci] * wp[ci * 3 + 2];
        xcv[o] = a;
        xc[boff + o * 1024 + t] = a;
    }
    float x1v[12];
#pragma unroll
    for (int o = 0; o < 12; o++) {
        float a = b2[o];
#pragma unroll
        for (int ci = 0; ci < 12; ci++) a += xcv[ci] * w2[o * 12 + ci];
        x1v[o] = a;
        x1[boff + o * 1024 + t] = a;
    }

    // LN2 stats on x1v (sred/sMR reuse is safe: all sMR reads happened
    // before the sync above)
#pragma unroll
    for (int ci = 0; ci < 12; ci++) {
        float s = x1v[ci], ss = x1v[ci] * x1v[ci];
#pragma unroll
        for (int off = 32; off >= 1; off >>= 1) {
            s += __shfl_xor(s, off); ss += __shfl_xor(ss, off);
        }
        if (la == 0) { sred[ci][w][0] = s; sred[ci][w][1] = ss; }
    }
    __syncthreads();
    if (w < 12 && la == 0) {
        float s = 0.f, ss = 0.f;
        for (int u = 0; u < 16; u++) { s += sred[w][u][0]; ss += sred[w][u][1]; }
        float mu = s * (1.f / 1024.f);
        float var = ss * (1.f / 1024.f) - mu * mu;
        sMR[w][0] = mu; sMR[w][1] = rsqrtf(var + 1e-5f);
    }
    __syncthreads();
    {
        const float g2 = xl_g[t], b2v = xl_b[t];
#pragma unroll
        for (int ci = 0; ci < 12; ci++) {
            float v = (x1v[ci] - sMR[ci][0]) * sMR[ci][1] * g2 + b2v;
            xn2b[boff + ci * 1024 + t] = f2b(v);
        }
    }
}

// ------------------------------ bf16 GEMM ----------------------------------
// C[m][n] = sum_k A[m][k]*BT[n][k] + bias[n]; 128x128 tile, 4 waves 2x2,
// each wave 64x64 via 4x4 of mfma_f32_16x16x32_bf16. Staging via
// global_load_lds width-16: thread t's dest byte = 16*t.
// MODE 0: store bf16.  MODE 2: y = silu(xc)*(acc+bias+x1) + skip, store fp32.

template <int MODE>
__global__ __launch_bounds__(256) void gemm_kernel(
    const unsigned short* __restrict__ A, const unsigned short* __restrict__ BT,
    const float* __restrict__ bias, void* __restrict__ out,
    int M, int N, int K,
    const float* __restrict__ xc, const float* __restrict__ x1,
    const float* __restrict__ skip)
{
    __shared__ __align__(16) unsigned short sA[128 * 32];
    __shared__ __align__(16) unsigned short sB[128 * 32];
    const int t = threadIdx.x;
    const int m0 = blockIdx.y * 128;
    const int n0 = blockIdx.x * 128;
    const int w = t >> 6;
    const int lane = t & 63;
    const int wr = (w >> 1) * 64;
    const int wc = (w & 1) * 64;
    const int lrow = lane & 15;
    const int quad = lane >> 4;
    const int row_l = t >> 2;          // 0..63
    const int cs = (t & 3) * 8;        // 0,8,16,24

    const unsigned short* gA0 = A + (size_t)(m0 + row_l) * K + cs;
    const unsigned short* gA1 = A + (size_t)(m0 + row_l + 64) * K + cs;
    const unsigned short* gB0 = BT + (size_t)(n0 + row_l) * K + cs;
    const unsigned short* gB1 = BT + (size_t)(n0 + row_l + 64) * K + cs;
    unsigned short* lA0 = sA + w * 512;          // wave-uniform LDS bases
    unsigned short* lA1 = sA + 2048 + w * 512;
    unsigned short* lB0 = sB + w * 512;
    unsigned short* lB1 = sB + 2048 + w * 512;

    floatx4 acc[4][4];
#pragma unroll
    for (int i = 0; i < 4; i++)
#pragma unroll
        for (int j = 0; j < 4; j++) acc[i][j] = (floatx4)0.f;

    for (int k0 = 0; k0 < K; k0 += 32) {
        __syncthreads();
        __builtin_amdgcn_global_load_lds((gu32*)(gA0 + k0), (lu32*)lA0, 16, 0, 0);
        __builtin_amdgcn_global_load_lds((gu32*)(gA1 + k0), (lu32*)lA1, 16, 0, 0);
        __builtin_amdgcn_global_load_lds((gu32*)(gB0 + k0), (lu32*)lB0, 16, 0, 0);
        __builtin_amdgcn_global_load_lds((gu32*)(gB1 + k0), (lu32*)lB1, 16, 0, 0);
        __syncthreads();
        short8_t af[4], bfr[4];
#pragma unroll
        for (int i = 0; i < 4; i++) {
            af[i] = *(const short8_t*)(sA + (wr + i * 16 + lrow) * 32 + quad * 8);
            bfr[i] = *(const short8_t*)(sB + (wc + i * 16 + lrow) * 32 + quad * 8);
        }
#pragma unroll
        for (int i = 0; i < 4; i++)
#pragma unroll
            for (int j = 0; j < 4; j++)
                acc[i][j] = __builtin_amdgcn_mfma_f32_16x16x32_bf16(
                    af[i], bfr[j], acc[i][j], 0, 0, 0);
    }

#pragma unroll
    for (int i = 0; i < 4; i++) {
#pragma unroll
        for (int j = 0; j < 4; j++) {
#pragma unroll
            for (int r = 0; r < 4; r++) {
                const int gm = m0 + wr + i * 16 + quad * 4 + r;
                const int gn = n0 + wc + j * 16 + lrow;
                const size_t idx = (size_t)gm * N + gn;
                float v = acc[i][j][r] + bias[gn];
                if (MODE == 0) {
                    ((unsigned short*)out)[idx] = f2b(v);
                } else {
                    float xcv = xc[idx];
                    float sig = xcv / (1.f + __expf(-xcv));
                    ((float*)out)[idx] = sig * (v + x1[idx]) + skip[idx];
                }
            }
        }
    }
}

// ------------------- sLSTM recurrence + GroupNorm (MFMA) -------------------
// grid (NH=8, B/16=32) = 256 blocks (1/CU), block 1024 (16 waves, 4/SIMD).
// Per step: rec(16x512) = h(16x128) @ Rg[head]^T(128x512) via 16x16x32 MFMA.

#define RECP 516   // f32 row stride for sRec (2-way bank aliasing only)
#define HBP  136   // bf16 row stride for sHb

__global__ __launch_bounds__(1024, 4) void slstm_rec_kernel(
    const float* __restrict__ Rg,             // [8][512][128] f32
    const unsigned short* __restrict__ gxb,   // [B][12][4096] bf16
    const float* __restrict__ gn_g, const float* __restrict__ gn_b,
    unsigned short* __restrict__ hnb)         // [B][12][1024] bf16
{
    __shared__ __align__(16) float sRec[16 * RECP];           // 33.0 KB
    __shared__ __align__(16) unsigned short sHb[16 * HBP];    // 4.4 KB
    const int head = blockIdx.x;
    const int b0 = blockIdx.y * 16;
    const int t = threadIdx.x;
    const int w = t >> 6;          // wave id = MFMA col-slice = state batch
    const int lane = t & 63;
    const int quad = lane >> 4;
    const int l16 = lane & 15;

    short8_t Bf[2][4];
    {
        const float* Rh = Rg + (size_t)head * 65536;
#pragma unroll
        for (int jt = 0; jt < 2; jt++)
#pragma unroll
            for (int kk = 0; kk < 4; kk++) {
                const float* src =
                    Rh + (size_t)(w * 32 + jt * 16 + l16) * 128 + kk * 32 + quad * 8;
                short8_t v;
#pragma unroll
                for (int j = 0; j < 8; j++) v[j] = (short)f2b(src[j]);
                Bf[jt][kk] = v;
            }
    }

    for (int i = t; i < 16 * HBP; i += 1024) sHb[i] = 0;

    const int la = lane;
    float c0 = 0.f, n0s = 0.f, m0 = 0.f;
    float c1 = 0.f, n1s = 0.f, m1 = 0.f;
    const float gg0 = gn_g[head * 128 + la];
    const float gg1 = gn_g[head * 128 + la + 64];
    const float gb0 = gn_b[head * 128 + la];
    const float gb1 = gn_b[head * 128 + la + 64];

    __syncthreads();

    for (int step = 0; step < 12; step++) {
        const unsigned short* gp =
            gxb + ((size_t)(b0 + w) * 12 + step) * 4096 + head * 512;
        float gz0 = b2f(gp[la]),       gz1 = b2f(gp[64 + la]);
        float gi0 = b2f(gp[128 + la]), gi1 = b2f(gp[192 + la]);
        float gf0 = b2f(gp[256 + la]), gf1 = b2f(gp[320 + la]);
        float go0 = b2f(gp[384 + la]), go1 = b2f(gp[448 + la]);

        short8_t Af[4];
#pragma unroll
        for (int kk = 0; kk < 4; kk++)
            Af[kk] = *(const short8_t*)(sHb + l16 * HBP + kk * 32 + quad * 8);
        floatx4 D0 = (floatx4)0.f, D1 = (floatx4)0.f;
#pragma unroll
        for (int kk = 0; kk < 4; kk++) {
            D0 = __builtin_amdgcn_mfma_f32_16x16x32_bf16(Af[kk], Bf[0][kk], D0, 0, 0, 0);
            D1 = __builtin_amdgcn_mfma_f32_16x16x32_bf16(Af[kk], Bf[1][kk], D1, 0, 0, 0);
        }
#pragma unroll
        for (int r = 0; r < 4; r++) {
            sRec[(quad * 4 + r) * RECP + w * 32 + l16] = D0[r];
            sRec[(quad * 4 + r) * RECP + w * 32 + 16 + l16] = D1[r];
        }
        __syncthreads();

        const float* rr = sRec + w * RECP;
        float zp0 = gz0 + rr[la],       zp1 = gz1 + rr[64 + la];
        float ip0 = gi0 + rr[128 + la], ip1 = gi1 + rr[192 + la];
        float fp0 = gf0 + rr[256 + la], fp1 = gf1 + rr[320 + la];
        float op0 = go0 + rr[384 + la], op1 = go1 + rr[448 + la];

        float e20 = __expf(2.f * zp0), e21 = __expf(2.f * zp1);
        float z0 = (e20 - 1.f) / (e20 + 1.f), z1 = (e21 - 1.f) / (e21 + 1.f);
        float o0 = 1.f / (1.f + __expf(-op0)), o1 = 1.f / (1.f + __expf(-op1));
        float mn0 = fmaxf(fp0 + m0, ip0), mn1 = fmaxf(fp1 + m1, ip1);
        float ie0 = __expf(ip0 - mn0), ie1 = __expf(ip1 - mn1);
        float fe0 = __expf(fp0 + m0 - mn0), fe1 = __expf(fp1 + m1 - mn1);
        c0 = fe0 * c0 + ie0 * z0;  c1 = fe1 * c1 + ie1 * z1;
        n0s = fe0 * n0s + ie0;     n1s = fe1 * n1s + ie1;
        m0 = mn0;                  m1 = mn1;
        float h0 = o0 * (c0 / n0s), h1 = o1 * (c1 / n1s);

        float s = h0 + h1, ss = h0 * h0 + h1 * h1;
#pragma unroll
        for (int off = 32; off >= 1; off >>= 1) {
            s += __shfl_xor(s, off);
            ss += __shfl_xor(ss, off);
        }
        float mu = s * (1.f / 128.f);
        float var = ss * (1.f / 128.f) - mu * mu;
        float rs = rsqrtf(var + 1e-5f);
        size_t base = ((size_t)(b0 + w) * 12 + step) * 1024 + head * 128;
        hnb[base + la] = f2b((h0 - mu) * rs * gg0 + gb0);
        hnb[base + la + 64] = f2b((h1 - mu) * rs * gg1 + gb1);

        sHb[w * HBP + la] = f2b(h0);
        sHb[w * HBP + la + 64] = f2b(h1);
        __syncthreads();
    }
}

// ------------------------------ gate kernel --------------------------------

__global__ __launch_bounds__(256) void gate_kernel(
    const unsigned short* __restrict__ lr, unsigned short* __restrict__ glr)
{
    size_t gid = (size_t)blockIdx.x * 256 + threadIdx.x;  // 6144*1024
    size_t m = gid >> 10;
    int j = (int)(gid & 1023);
    float lf = b2f(lr[m * 2048 + j]);
    float rt = b2f(lr[m * 2048 + 1024 + j]);
    glr[gid] = f2b(gelu_exact(lf) * rt);
}

// ---------------- fused tail: conv1+gelu+LN(len)+conv2+skip ----------------
// grid 512 (one block per batch), block 512 (8 waves), 2 blocks/CU (74 KB).
// Thread owns positions (p, p+512): all conv FMAs packed (v_pk_fma_f32) with
// SGPR weight broadcast. Channel halves (24 of 48) keep sZ in 49 KB; conv2
// accumulates partials across halves. z normalized in place before conv2.

__global__ __launch_bounds__(512, 4) void tail_fused_kernel(
    const float* __restrict__ y, const float* __restrict__ skip,
    const float* __restrict__ w1, const float* __restrict__ b1,
    const float* __restrict__ w2, const float* __restrict__ b2,
    const float* __restrict__ lng, const float* __restrict__ lnb,
    float* __restrict__ out)
{
    __shared__ unsigned short sY[12][1026];   // 24.6 KB
    __shared__ unsigned short sZ[24][1026];   // 49.2 KB
    __shared__ float sMR[24][2];
    const int b = blockIdx.x;
    const int p = threadIdx.x;                // positions p, p+512
    const size_t boff = (size_t)b * 12288;

    {
#pragma unroll
        for (int ci = 0; ci < 12; ci++) {
            sY[ci][p] = f2b(y[boff + ci * 1024 + p]);
            sY[ci][p + 512] = f2b(y[boff + ci * 1024 + p + 512]);
        }
    }
    const float lg0 = lng[p], lb0 = lnb[p];
    const float lg1 = lng[p + 512], lb1 = lnb[p + 512];
    __syncthreads();

    float2_t acc[12];
#pragma unroll
    for (int o = 0; o < 12; o++) { float bv = b2[o]; acc[o] = float2_t{bv, bv}; }

    for (int half = 0; half < 2; half++) {
        // conv1 inputs, packed over the 2 positions (reloaded per half to
        // bound register lifetime)
        float2_t vm[12], v0[12], vp[12];
#pragma unroll
        for (int ci = 0; ci < 12; ci++) {
            v0[ci] = float2_t{b2f(sY[ci][p]), b2f(sY[ci][p + 512])};
            vm[ci] = float2_t{(p > 0) ? b2f(sY[ci][p - 1]) : 0.f,
                              b2f(sY[ci][p + 511])};
            vp[ci] = float2_t{b2f(sY[ci][p + 1]),
                              (p < 511) ? b2f(sY[ci][p + 513]) : 0.f};
        }
        // conv1 (12 -> 24 channels of this half) + gelu
        for (int o = 0; o < 24; o++) {
            const float* wp = w1 + (half * 24 + o) * 36;   // uniform -> SGPR
            float bo = b1[half * 24 + o];
            float2_t a = float2_t{bo, bo};
#pragma unroll
            for (int ci = 0; ci < 12; ci++)
                a += vm[ci] * wp[ci * 3] + v0[ci] * wp[ci * 3 + 1]
                   + vp[ci] * wp[ci * 3 + 2];
            sZ[o][p] = f2b(gelu_fast(a.x));
            sZ[o][p + 512] = f2b(gelu_fast(a.y));
        }
        __syncthreads();

        // LN stats over length: wave w handles channels w, w+8, w+16
        {
            const int w = p >> 6, la = p & 63;
#pragma unroll
            for (int j = 0; j < 3; j++) {
                const int ch = w + j * 8;
                float s = 0.f, ss = 0.f;
#pragma unroll
                for (int u = 0; u < 16; u++) {
                    float v = b2f(sZ[ch][la + u * 64]);
                    s += v; ss += v * v;
                }
#pragma unroll
                for (int off = 32; off >= 1; off >>= 1) {
                    s += __shfl_xor(s, off); ss += __shfl_xor(ss, off);
                }
                if (la == 0) {
                    float mu = s * (1.f / 1024.f);
                    float var = ss * (1.f / 1024.f) - mu * mu;
                    sMR[ch][0] = mu;
                    sMR[ch][1] = rsqrtf(var + 1e-5f);
                }
            }
        }
        __syncthreads();

        // normalize z in place (own slots only -> own lng/lnb)
#pragma unroll
        for (int ch = 0; ch < 24; ch++) {
            float mu = sMR[ch][0], rs = sMR[ch][1];
            sZ[ch][p] = f2b((b2f(sZ[ch][p]) - mu) * rs * lg0 + lb0);
            sZ[ch][p + 512] = f2b((b2f(sZ[ch][p + 512]) - mu) * rs * lg1 + lb1);
        }
        __syncthreads();

        // conv2 partial over this half's 24 input channels
        for (int ci = 0; ci < 24; ci++) {
            float2_t zm = float2_t{(p > 0) ? b2f(sZ[ci][p - 1]) : 0.f,
                                   b2f(sZ[ci][p + 511])};
            float2_t z0 = float2_t{b2f(sZ[ci][p]), b2f(sZ[ci][p + 512])};
            float2_t zp = float2_t{b2f(sZ[ci][p + 1]),
                                   (p < 511) ? b2f(sZ[ci][p + 513]) : 0.f};
            const float* wp = w2 + (half * 24 + ci) * 3;   // uniform -> SGPR
#pragma unroll
            for (int o = 0; o < 12; o++)
                acc[o] += zm * wp[o * 144] + z0 * wp[o * 144 + 1]
                        + zp * wp[o * 144 + 2];
        }
        __syncthreads();   // before next half overwrites sZ
    }

#pragma unroll
    for (int o = 0; o < 12; o++) {
        size_t i0 = boff + (size_t)o * 1024 + p;
        out[i0] = acc[o].x + skip[i0];
        out[i0 + 512] = acc[o].y + skip[i0 + 512];
    }
}

// ------------------------------ launcher -----------------------------------

extern "C" void kernel_launch(void* const* d_in, const int* in_sizes, int n_in,
                              void* d_out, int out_size, void* d_ws, size_t ws_size,
                              hipStream_t stream)
{
    (void)in_sizes; (void)n_in; (void)out_size; (void)ws_size;
    const float* x      = (const float*)d_in[0];
    const float* ln_g   = (const float*)d_in[1];
    const float* ln_b   = (const float*)d_in[2];
    const float* fc1_w  = (const float*)d_in[3];
    const float* fc1_b  = (const float*)d_in[4];
    const float* fc2_w  = (const float*)d_in[5];
    const float* fc2_b  = (const float*)d_in[6];
    const float* conv1_w= (const float*)d_in[7];
    const float* conv1_b= (const float*)d_in[8];
    const float* conv2_w= (const float*)d_in[9];
    const float* conv2_b= (const float*)d_in[10];
    const float* xl_g   = (const float*)d_in[11];
    const float* xl_b   = (const float*)d_in[12];
    const float* Wg     = (const float*)d_in[13];
    const float* bg     = (const float*)d_in[14];
    const float* Rg     = (const float*)d_in[15];
    const float* gn_g   = (const float*)d_in[16];
    const float* gn_b   = (const float*)d_in[17];
    const float* upl_w  = (const float*)d_in[18];
    const float* upl_b  = (const float*)d_in[19];
    const float* upr_w  = (const float*)d_in[20];
    const float* upr_b  = (const float*)d_in[21];
    const float* down_w = (const float*)d_in[22];
    const float* down_b = (const float*)d_in[23];

    char* ws = (char*)d_ws;
    size_t off = 0;
    auto alloc = [&](size_t bytes) -> char* {
        char* p = ws + off;
        off = (off + bytes + 255) & ~(size_t)255;
        return p;
    };
    float* xn            = (float*)alloc(25165824);          // 6144x1024 f32
    float* xc            = (float*)alloc(25165824);
    float* x1            = (float*)alloc(25165824);
    unsigned short* xn2b = (unsigned short*)alloc(12582912); // 6144x1024 bf16
    unsigned short* gxb  = (unsigned short*)alloc(50331648); // 6144x4096 bf16
    unsigned short* hnb  = (unsigned short*)alloc(12582912);
    unsigned short* lrb  = (unsigned short*)alloc(25165824); // 6144x2048 bf16
    unsigned short* glrb = (unsigned short*)alloc(12582912);
    float* yb            = (float*)alloc(25165824);
    unsigned short* WgT  = (unsigned short*)alloc(8388608);  // 4096x1024 bf16
    unsigned short* WupT = (unsigned short*)alloc(4194304);  // 2048x1024 bf16
    unsigned short* WdT  = (unsigned short*)alloc(2097152);  // 1024x1024 bf16
    float* bup           = (float*)alloc(8192);              // 2048 f32

    // weight prep
    transpose_bf16_k<<<dim3(128, 32), 256, 0, stream>>>(Wg, WgT, 1024, 4096);
    transpose_bf16_k<<<dim3(32, 32), 256, 0, stream>>>(upl_w, WupT, 1024, 1024);
    transpose_bf16_k<<<dim3(32, 32), 256, 0, stream>>>(upr_w, WupT + 1024 * 1024, 1024, 1024);
    transpose_bf16_k<<<dim3(32, 32), 256, 0, stream>>>(down_w, WdT, 1024, 1024);
    cat_bias_k<<<8, 256, 0, stream>>>(upl_b, upr_b, bup);

    // main pipeline
    frontend_fused_kernel<<<512, 1024, 0, stream>>>(
        x, ln_g, ln_b, fc1_w, fc1_b, fc2_w, fc2_b, xl_g, xl_b,
        xn, xc, x1, xn2b);
    gemm_kernel<0><<<dim3(32, 48), 256, 0, stream>>>(
        xn2b, WgT, bg, gxb, 6144, 4096, 1024, nullptr, nullptr, nullptr);
    slstm_rec_kernel<<<dim3(8, 32), 1024, 0, stream>>>(Rg, gxb, gn_g, gn_b, hnb);
    gemm_kernel<0><<<dim3(16, 48), 256, 0, stream>>>(
        hnb, WupT, bup, lrb, 6144, 2048, 1024, nullptr, nullptr, nullptr);
    gate_kernel<<<24576, 256, 0, stream>>>(lrb, glrb);
    gemm_kernel<2><<<dim3(8, 48), 256, 0, stream>>>(
        glrb, WdT, down_b, yb, 6144, 1024, 1024, xc, x1, xn);
    tail_fused_kernel<<<512, 512, 0, stream>>>(
        yb, xn, conv1_w, conv1_b, conv2_w, conv2_b, ln_g, ln_b, (float*)d_out);
}